// Round 6
// baseline (1602.278 us; speedup 1.0000x reference)
//
#include <hip/hip_runtime.h>
#include <hip/hip_bf16.h>
#include <type_traits>

// ---------------- CSR build ----------------
__global__ void hist_kernel(const int* __restrict__ src, const int* __restrict__ dst,
                            int* __restrict__ deg_out, int* __restrict__ deg_in, int E) {
    int e = blockIdx.x * blockDim.x + threadIdx.x;
    if (e < E) {
        atomicAdd(&deg_out[src[e]], 1);
        atomicAdd(&deg_in[dst[e]], 1);
    }
}

__global__ void scan_kernel(const int* __restrict__ deg, int* __restrict__ row_ptr,
                            int* __restrict__ cursor, int n) {
    __shared__ int wsum[16];
    __shared__ int running;
    int tid = threadIdx.x, lane = tid & 63, wid = tid >> 6;
    if (tid == 0) running = 0;
    __syncthreads();
    for (int base = 0; base < n; base += 1024) {
        int i = base + tid;
        int v = (i < n) ? deg[i] : 0;
        int incl = v;
        #pragma unroll
        for (int off = 1; off < 64; off <<= 1) {
            int t = __shfl_up(incl, off);
            if (lane >= off) incl += t;
        }
        if (lane == 63) wsum[wid] = incl;
        __syncthreads();
        if (wid == 0 && lane < 16) {
            int s = wsum[lane], si = s;
            #pragma unroll
            for (int off = 1; off < 16; off <<= 1) {
                int t = __shfl_up(si, off);
                if (lane >= off) si += t;
            }
            wsum[lane] = si - s;  // exclusive
        }
        __syncthreads();
        int excl = running + wsum[wid] + (incl - v);
        if (i < n) { row_ptr[i] = excl; cursor[i] = excl; }
        __syncthreads();
        if (tid == 1023) running = excl + v;
        __syncthreads();
    }
    if (tid == 0) row_ptr[n] = running;
}

__global__ void fill_kernel(const int* __restrict__ src, const int* __restrict__ dst,
                            int* __restrict__ cursor, int* __restrict__ col, int E) {
    int e = blockIdx.x * blockDim.x + threadIdx.x;
    if (e < E) {
        int p = atomicAdd(&cursor[dst[e]], 1);
        col[p] = src[e];
    }
}

// deterministic neighbor order: insertion-sort each CSR row (avg deg 16)
__global__ void sort_rows_kernel(const int* __restrict__ row_ptr, int* __restrict__ col, int n) {
    int v = blockIdx.x * blockDim.x + threadIdx.x;
    if (v >= n) return;
    int e0 = row_ptr[v], e1 = row_ptr[v + 1];
    for (int i = e0 + 1; i < e1; ++i) {
        int key = col[i];
        int j = i - 1;
        while (j >= e0 && col[j] > key) { col[j + 1] = col[j]; --j; }
        col[j + 1] = key;
    }
}

// ---------------- masked degrees ----------------
__global__ void out_deg_mask_kernel(const int* __restrict__ src, const int* __restrict__ dst,
                                    const float* __restrict__ m, float* __restrict__ so, int E) {
    int e = blockIdx.x * blockDim.x + threadIdx.x;
    if (e < E) {
        float md = m[dst[e]];
        if (md != 0.f) atomicAdd(&so[src[e]], md);
    }
}

__global__ void in_deg_mask_kernel(const int* __restrict__ row_ptr, const int* __restrict__ col,
                                   const float* __restrict__ m, float* __restrict__ si, int n) {
    int v = blockIdx.x * blockDim.x + threadIdx.x;
    if (v < n) {
        float s = 0.f;
        int e1 = row_ptr[v + 1];
        for (int e = row_ptr[v]; e < e1; ++e) s += m[col[e]];
        si[v] = s;
    }
}

__global__ void scale_full_kernel(const int* __restrict__ dout, const int* __restrict__ din,
                                  float* __restrict__ s, float* __restrict__ t, int n) {
    int v = blockIdx.x * blockDim.x + threadIdx.x;
    if (v < n) {
        s[v] = 1.f / sqrtf((float)max(dout[v], 1));
        t[v] = 1.f / sqrtf((float)max(din[v], 1));
    }
}

__global__ void scale_mask_kernel(const float* __restrict__ gate, const float* __restrict__ mask,
                                  const float* __restrict__ so, const float* __restrict__ si,
                                  float* __restrict__ s, float* __restrict__ t, int n) {
    int v = blockIdx.x * blockDim.x + threadIdx.x;
    if (v < n) {
        s[v] = gate[v] * (1.f / sqrtf(fmaxf(so[v], 1.f)));
        t[v] = mask[v] * (1.f / sqrtf(fmaxf(si[v], 1.f)));
    }
}

// ---------------- split-bf16 helpers ----------------
__device__ __forceinline__ unsigned short f2bf(float x) {
    unsigned u = __float_as_uint(x);
    unsigned r = u + 0x7fffu + ((u >> 16) & 1u);   // RNE
    return (unsigned short)(r >> 16);
}
__device__ __forceinline__ float bf2f(unsigned short h) {
    return __uint_as_float(((unsigned)h) << 16);
}
__device__ __forceinline__ void split4(float x, float y, float z, float w,
                                       ushort4& hv, ushort4& lv) {
    hv.x = f2bf(x); lv.x = f2bf(x - bf2f(hv.x));
    hv.y = f2bf(y); lv.y = f2bf(y - bf2f(hv.y));
    hv.z = f2bf(z); lv.z = f2bf(z - bf2f(hv.z));
    hv.w = f2bf(w); lv.w = f2bf(w - bf2f(hv.w));
}

typedef __attribute__((ext_vector_type(8))) short short8v;
typedef __attribute__((ext_vector_type(4))) float f32x4;

// ---------------- aggregation from f32 FEATURES, F=128 (full graph, row-major) ----------------
template <bool SPLIT>
__global__ void agg_feat_128_kernel(const int* __restrict__ row_ptr, const int* __restrict__ col,
                                    const float* __restrict__ X, const float* __restrict__ s,
                                    const float* __restrict__ t, float* __restrict__ out,
                                    unsigned short* __restrict__ oh, unsigned short* __restrict__ ol,
                                    int n) {
    int tid = threadIdx.x;
    int node = blockIdx.x * 8 + (tid >> 5);
    int f4 = tid & 31;
    if (node >= n) return;
    int e0 = row_ptr[node], e1 = row_ptr[node + 1];
    const float4* X4 = (const float4*)X;
    float ax = 0.f, ay = 0.f, az = 0.f, aw = 0.f;
    int e = e0;
    for (; e + 3 < e1; e += 4) {
        int u0 = col[e], u1 = col[e + 1], u2 = col[e + 2], u3 = col[e + 3];
        float s0 = s[u0], s1 = s[u1], s2 = s[u2], s3 = s[u3];
        float4 x0 = X4[(size_t)u0 * 32 + f4];
        float4 x1 = X4[(size_t)u1 * 32 + f4];
        float4 x2 = X4[(size_t)u2 * 32 + f4];
        float4 x3 = X4[(size_t)u3 * 32 + f4];
        ax += s0 * x0.x; ay += s0 * x0.y; az += s0 * x0.z; aw += s0 * x0.w;
        ax += s1 * x1.x; ay += s1 * x1.y; az += s1 * x1.z; aw += s1 * x1.w;
        ax += s2 * x2.x; ay += s2 * x2.y; az += s2 * x2.z; aw += s2 * x2.w;
        ax += s3 * x3.x; ay += s3 * x3.y; az += s3 * x3.z; aw += s3 * x3.w;
    }
    for (; e < e1; ++e) {
        int u = col[e];
        float sc = s[u];
        float4 q = X4[(size_t)u * 32 + f4];
        ax += sc * q.x; ay += sc * q.y; az += sc * q.z; aw += sc * q.w;
    }
    float tv = t[node];
    if (SPLIT) {
        ushort4 hv, lv;
        split4(ax * tv, ay * tv, az * tv, aw * tv, hv, lv);
        *(ushort4*)&oh[(size_t)node * 128 + f4 * 4] = hv;
        *(ushort4*)&ol[(size_t)node * 128 + f4 * 4] = lv;
    } else {
        float4 r; r.x = ax * tv; r.y = ay * tv; r.z = az * tv; r.w = aw * tv;
        ((float4*)out)[(size_t)node * 32 + f4] = r;
    }
}

// ============ R18: chunk-major 256-wide aggregation (XCD-L2-resident) ============
// Input Xcm laid out [16 chunks][NPAD nodes][16 floats]. One chunk slice =
// NPAD*64B ~ 3.2 MB < 4 MiB L2, and 64B node-slices are cache-LINE-PURE
// (a 128B line holds 2 nodes of the SAME chunk) -- fixes R17's fragmentation.
// Grid [phase(2)][group][8]: chunk = phase*8 + blockIdx&7; with round-robin
// block->XCD dispatch each XCD keeps one slice L2-resident per phase.
// col[] streamed nontemporal (16x duplicated read must not evict the slice).
// Per-output accumulation order identical to row-major version -> bit-identical.
template <bool MASKED>
__global__ void agg_cm_256_kernel(const int* __restrict__ row_ptr, const int* __restrict__ col,
                                  const float* __restrict__ Xcm, const float* __restrict__ s,
                                  const float* __restrict__ t,
                                  unsigned short* __restrict__ oh, unsigned short* __restrict__ ol,
                                  int n, int NPAD, int G) {
    int tid = threadIdx.x;
    int bid = blockIdx.x;
    int x = bid & 7;
    int rest = bid >> 3;
    int p = rest / G;
    int g = rest - p * G;
    int chunk = p * 8 + x;
    int node = g * 64 + (tid >> 2);
    int q = tid & 3;
    if (node >= n) return;
    float tv = t[node];
    if (MASKED && tv == 0.f) return;
    int e0 = row_ptr[node], e1 = row_ptr[node + 1];
    const float4* Xc = (const float4*)Xcm + (size_t)chunk * NPAD * 4 + q;
    float ax = 0.f, ay = 0.f, az = 0.f, aw = 0.f;
    int e = e0;
    for (; e + 3 < e1; e += 4) {
        int u0 = __builtin_nontemporal_load(&col[e]);
        int u1 = __builtin_nontemporal_load(&col[e + 1]);
        int u2 = __builtin_nontemporal_load(&col[e + 2]);
        int u3 = __builtin_nontemporal_load(&col[e + 3]);
        float s0 = s[u0], s1 = s[u1], s2 = s[u2], s3 = s[u3];
        if (!MASKED) {
            float4 x0 = Xc[(size_t)u0 * 4];
            float4 x1 = Xc[(size_t)u1 * 4];
            float4 x2 = Xc[(size_t)u2 * 4];
            float4 x3 = Xc[(size_t)u3 * 4];
            ax += s0 * x0.x; ay += s0 * x0.y; az += s0 * x0.z; aw += s0 * x0.w;
            ax += s1 * x1.x; ay += s1 * x1.y; az += s1 * x1.z; aw += s1 * x1.w;
            ax += s2 * x2.x; ay += s2 * x2.y; az += s2 * x2.z; aw += s2 * x2.w;
            ax += s3 * x3.x; ay += s3 * x3.y; az += s3 * x3.z; aw += s3 * x3.w;
        } else {
            if (s0 != 0.f) { float4 v = Xc[(size_t)u0 * 4];
                ax += s0 * v.x; ay += s0 * v.y; az += s0 * v.z; aw += s0 * v.w; }
            if (s1 != 0.f) { float4 v = Xc[(size_t)u1 * 4];
                ax += s1 * v.x; ay += s1 * v.y; az += s1 * v.z; aw += s1 * v.w; }
            if (s2 != 0.f) { float4 v = Xc[(size_t)u2 * 4];
                ax += s2 * v.x; ay += s2 * v.y; az += s2 * v.z; aw += s2 * v.w; }
            if (s3 != 0.f) { float4 v = Xc[(size_t)u3 * 4];
                ax += s3 * v.x; ay += s3 * v.y; az += s3 * v.z; aw += s3 * v.w; }
        }
    }
    for (; e < e1; ++e) {
        int u = __builtin_nontemporal_load(&col[e]);
        float sc = s[u];
        if (!MASKED || sc != 0.f) {
            float4 v = Xc[(size_t)u * 4];
            ax += sc * v.x; ay += sc * v.y; az += sc * v.z; aw += sc * v.w;
        }
    }
    ushort4 hv, lv;
    split4(ax * tv, ay * tv, az * tv, aw * tv, hv, lv);
    size_t o = (size_t)node * 256 + chunk * 16 + q * 4;
    // ushort4 is 8B and 8B-aligned here; nontemporal store requires scalar type
    __builtin_nontemporal_store(*(const unsigned long long*)&hv, (unsigned long long*)&oh[o]);
    __builtin_nontemporal_store(*(const unsigned long long*)&lv, (unsigned long long*)&ol[o]);
}

// legacy row-major 256-wide agg (non-fast fallback only)
template <bool MASKED, bool SPLIT>
__global__ void agg_f32_256_kernel(const int* __restrict__ row_ptr, const int* __restrict__ col,
                                   const float* __restrict__ X, const float* __restrict__ s,
                                   const float* __restrict__ t, float* __restrict__ out,
                                   unsigned short* __restrict__ oh, unsigned short* __restrict__ ol,
                                   int n) {
    int tid = threadIdx.x;
    int node = blockIdx.x * 4 + (tid >> 6);
    int f4 = tid & 63;
    if (node >= n) return;
    float tv = t[node];
    if (MASKED && tv == 0.f) return;
    int e0 = row_ptr[node], e1 = row_ptr[node + 1];
    const float4* X4 = (const float4*)X;
    float ax = 0.f, ay = 0.f, az = 0.f, aw = 0.f;
    int e = e0;
    for (; e + 3 < e1; e += 4) {
        int u0 = col[e], u1 = col[e + 1], u2 = col[e + 2], u3 = col[e + 3];
        float s0 = s[u0], s1 = s[u1], s2 = s[u2], s3 = s[u3];
        if (!MASKED) {
            float4 x0 = X4[(size_t)u0 * 64 + f4];
            float4 x1 = X4[(size_t)u1 * 64 + f4];
            float4 x2 = X4[(size_t)u2 * 64 + f4];
            float4 x3 = X4[(size_t)u3 * 64 + f4];
            ax += s0 * x0.x; ay += s0 * x0.y; az += s0 * x0.z; aw += s0 * x0.w;
            ax += s1 * x1.x; ay += s1 * x1.y; az += s1 * x1.z; aw += s1 * x1.w;
            ax += s2 * x2.x; ay += s2 * x2.y; az += s2 * x2.z; aw += s2 * x2.w;
            ax += s3 * x3.x; ay += s3 * x3.y; az += s3 * x3.z; aw += s3 * x3.w;
        } else {
            if (s0 != 0.f) { float4 v = X4[(size_t)u0 * 64 + f4];
                ax += s0 * v.x; ay += s0 * v.y; az += s0 * v.z; aw += s0 * v.w; }
            if (s1 != 0.f) { float4 v = X4[(size_t)u1 * 64 + f4];
                ax += s1 * v.x; ay += s1 * v.y; az += s1 * v.z; aw += s1 * v.w; }
            if (s2 != 0.f) { float4 v = X4[(size_t)u2 * 64 + f4];
                ax += s2 * v.x; ay += s2 * v.y; az += s2 * v.z; aw += s2 * v.w; }
            if (s3 != 0.f) { float4 v = X4[(size_t)u3 * 64 + f4];
                ax += s3 * v.x; ay += s3 * v.y; az += s3 * v.z; aw += s3 * v.w; }
        }
    }
    for (; e < e1; ++e) {
        int u = col[e];
        float sc = s[u];
        if (!MASKED || sc != 0.f) {
            float4 xv = X4[(size_t)u * 64 + f4];
            ax += sc * xv.x; ay += sc * xv.y; az += sc * xv.z; aw += sc * xv.w;
        }
    }
    if (SPLIT) {
        ushort4 hv, lv;
        split4(ax * tv, ay * tv, az * tv, aw * tv, hv, lv);
        *(ushort4*)&oh[(size_t)node * 256 + f4 * 4] = hv;
        *(ushort4*)&ol[(size_t)node * 256 + f4 * 4] = lv;
    } else {
        float4 r; r.x = ax * tv; r.y = ay * tv; r.z = az * tv; r.w = aw * tv;
        ((float4*)out)[(size_t)node * 64 + f4] = r;
    }
}

// ---------------- post-GEMM 128-dim gather for dec1 (row-major) ----------------
__global__ void agg_bias_128_kernel(const int* __restrict__ row_ptr, const int* __restrict__ col,
                                    const float* __restrict__ P, const float* __restrict__ t,
                                    const float* __restrict__ bias, float* __restrict__ out, int n) {
    int tid = threadIdx.x;
    int node = blockIdx.x * 8 + (tid >> 5);
    int f4 = tid & 31;
    if (node >= n) return;
    int e0 = row_ptr[node], e1 = row_ptr[node + 1];
    const float4* P4 = (const float4*)P;
    float ax = 0.f, ay = 0.f, az = 0.f, aw = 0.f;
    int e = e0;
    for (; e + 3 < e1; e += 4) {
        int u0 = col[e], u1 = col[e + 1], u2 = col[e + 2], u3 = col[e + 3];
        float4 x0 = P4[(size_t)u0 * 32 + f4];
        float4 x1 = P4[(size_t)u1 * 32 + f4];
        float4 x2 = P4[(size_t)u2 * 32 + f4];
        float4 x3 = P4[(size_t)u3 * 32 + f4];
        ax += x0.x; ay += x0.y; az += x0.z; aw += x0.w;
        ax += x1.x; ay += x1.y; az += x1.z; aw += x1.w;
        ax += x2.x; ay += x2.y; az += x2.z; aw += x2.w;
        ax += x3.x; ay += x3.y; az += x3.z; aw += x3.w;
    }
    for (; e < e1; ++e) {
        int u = col[e];
        float4 q = P4[(size_t)u * 32 + f4];
        ax += q.x; ay += q.y; az += q.z; aw += q.w;
    }
    float tv = t[node];
    float4 bv = ((const float4*)bias)[f4];
    float4 r;
    r.x = ax * tv + bv.x; r.y = ay * tv + bv.y;
    r.z = az * tv + bv.z; r.w = aw * tv + bv.w;
    ((float4*)out)[(size_t)node * 32 + f4] = r;
}

// ================= split-bf16 MFMA GEMM =================
// f32 GEMM emulated as Ah@Wh + Ah@Wl + Al@Wh; operands pre-split. 128x128 tile.
// R18: C written CHUNK-MAJOR [16][NPAD][16] for the downstream cm aggregation.

// one-shot: split+transpose all 6 weight matrices into [N][K] hi/lo planes
__global__ void wsplit_all_kernel(const float* __restrict__ W0, const float* __restrict__ W1,
                                  const float* __restrict__ W2, const float* __restrict__ W3,
                                  const float* __restrict__ W4, const float* __restrict__ W5,
                                  unsigned short* __restrict__ H, unsigned short* __restrict__ L) {
    int i = blockIdx.x * blockDim.x + threadIdx.x;
    const float* W; int rel, base, outIdx;
    if (i < 32768) { W = W0; rel = i; base = 0;
        int k = rel >> 8, nn = rel & 255; outIdx = nn * 128 + k; }
    else if (i < 98304) { W = W1; rel = i - 32768; base = 32768;
        int k = rel >> 8, nn = rel & 255; outIdx = nn * 256 + k; }
    else if (i < 163840) { W = W2; rel = i - 98304; base = 98304;
        int k = rel >> 8, nn = rel & 255; outIdx = nn * 256 + k; }
    else if (i < 229376) { W = W3; rel = i - 163840; base = 163840;
        int k = rel >> 8, nn = rel & 255; outIdx = nn * 256 + k; }
    else if (i < 294912) { W = W4; rel = i - 229376; base = 229376;
        int k = rel >> 8, nn = rel & 255; outIdx = nn * 256 + k; }
    else { W = W5; rel = i - 294912; base = 294912;
        int k = rel >> 7, nn = rel & 127; outIdx = nn * 256 + k; }
    float x = W[rel];
    unsigned short h = f2bf(x);
    H[base + outIdx] = h;
    L[base + outIdx] = f2bf(x - bf2f(h));
}

// full-rows 128x128 MFMA GEMM; Nn=256, chunk-major C
template <bool RELU>
__global__ __launch_bounds__(256, 3) void gemm_mfma_kernel(
    const unsigned short* __restrict__ Ah, const unsigned short* __restrict__ Al,
    const unsigned short* __restrict__ Wh, const unsigned short* __restrict__ Wl,
    const float* __restrict__ bias, float* __restrict__ C, int M, int K, int NPAD) {
    __shared__ __align__(16) short sAh[128][40];
    __shared__ __align__(16) short sAl[128][40];
    __shared__ __align__(16) short sWh[128][40];
    __shared__ __align__(16) short sWl[128][40];
    int tid = threadIdx.x;
    int bm = blockIdx.x * 128, bn = blockIdx.y * 128;
    int lane = tid & 63, wid = tid >> 6;
    int wr = (wid >> 1) * 64, wc = (wid & 1) * 64;
    int lr = lane & 15, kg = lane >> 4;
    int arow = tid >> 1, akq = (tid & 1) * 16;
    const unsigned short* ahp = Ah + (size_t)(bm + arow) * K + akq;
    const unsigned short* alp = Al + (size_t)(bm + arow) * K + akq;
    const unsigned short* whp = Wh + (size_t)(bn + arow) * K + akq;
    const unsigned short* wlp = Wl + (size_t)(bn + arow) * K + akq;
    f32x4 acc[4][4];
    #pragma unroll
    for (int i = 0; i < 4; ++i)
        #pragma unroll
        for (int j = 0; j < 4; ++j) acc[i][j] = (f32x4){0.f, 0.f, 0.f, 0.f};
    for (int k0 = 0; k0 < K; k0 += 32) {
        short8v a0 = *(const short8v*)(ahp + k0);
        short8v a1 = *(const short8v*)(ahp + k0 + 8);
        short8v l0 = *(const short8v*)(alp + k0);
        short8v l1 = *(const short8v*)(alp + k0 + 8);
        short8v w0 = *(const short8v*)(whp + k0);
        short8v w1 = *(const short8v*)(whp + k0 + 8);
        short8v v0 = *(const short8v*)(wlp + k0);
        short8v v1 = *(const short8v*)(wlp + k0 + 8);
        __syncthreads();
        *(short8v*)&sAh[arow][akq] = a0; *(short8v*)&sAh[arow][akq + 8] = a1;
        *(short8v*)&sAl[arow][akq] = l0; *(short8v*)&sAl[arow][akq + 8] = l1;
        *(short8v*)&sWh[arow][akq] = w0; *(short8v*)&sWh[arow][akq + 8] = w1;
        *(short8v*)&sWl[arow][akq] = v0; *(short8v*)&sWl[arow][akq + 8] = v1;
        __syncthreads();
        short8v ah[4], al[4];
        #pragma unroll
        for (int mf = 0; mf < 4; ++mf) {
            ah[mf] = *(const short8v*)&sAh[wr + mf * 16 + lr][kg * 8];
            al[mf] = *(const short8v*)&sAl[wr + mf * 16 + lr][kg * 8];
        }
        #pragma unroll
        for (int nf = 0; nf < 4; ++nf) {
            short8v bh = *(const short8v*)&sWh[wc + nf * 16 + lr][kg * 8];
            short8v bl = *(const short8v*)&sWl[wc + nf * 16 + lr][kg * 8];
            #pragma unroll
            for (int mf = 0; mf < 4; ++mf) {
                acc[mf][nf] = __builtin_amdgcn_mfma_f32_16x16x32_bf16(ah[mf], bh, acc[mf][nf], 0, 0, 0);
                acc[mf][nf] = __builtin_amdgcn_mfma_f32_16x16x32_bf16(ah[mf], bl, acc[mf][nf], 0, 0, 0);
                acc[mf][nf] = __builtin_amdgcn_mfma_f32_16x16x32_bf16(al[mf], bh, acc[mf][nf], 0, 0, 0);
            }
        }
    }
    #pragma unroll
    for (int mf = 0; mf < 4; ++mf) {
        #pragma unroll
        for (int nf = 0; nf < 4; ++nf) {
            int colg = bn + wc + nf * 16 + lr;
            int ck = colg >> 4, cw = colg & 15;
            float bv = bias ? bias[colg] : 0.f;
            float* cbase = C + (size_t)ck * NPAD * 16 + cw;
            #pragma unroll
            for (int r = 0; r < 4; ++r) {
                int grow = bm + wr + mf * 16 + kg * 4 + r;
                if (grow < M) {
                    float x = acc[mf][nf][r] + bv;
                    if (RELU) x = fmaxf(x, 0.f);
                    cbase[(size_t)grow * 16] = x;
                }
            }
        }
    }
}

// compacted-row-list variant (enc1 / bot / dec0); chunk-major C
template <bool RELU>
__global__ __launch_bounds__(256, 3) void gemm_rows_mfma_kernel(
    const unsigned short* __restrict__ Ah, const unsigned short* __restrict__ Al,
    const unsigned short* __restrict__ Wh, const unsigned short* __restrict__ Wl,
    const float* __restrict__ bias, const int* __restrict__ idx, int Mc,
    float* __restrict__ C, int K, int NPAD) {
    __shared__ __align__(16) short sAh[128][40];
    __shared__ __align__(16) short sAl[128][40];
    __shared__ __align__(16) short sWh[128][40];
    __shared__ __align__(16) short sWl[128][40];
    __shared__ int ridx[128];
    int tid = threadIdx.x;
    int bm = blockIdx.x * 128, bn = blockIdx.y * 128;
    int lane = tid & 63, wid = tid >> 6;
    int wr = (wid >> 1) * 64, wc = (wid & 1) * 64;
    int lr = lane & 15, kg = lane >> 4;
    int arow = tid >> 1, akq = (tid & 1) * 16;
    if (tid < 128) {
        int r = bm + tid;
        ridx[tid] = (r < Mc) ? idx[r] : idx[0];
    }
    __syncthreads();
    int rA = ridx[arow];
    const unsigned short* ahp = Ah + (size_t)rA * K + akq;
    const unsigned short* alp = Al + (size_t)rA * K + akq;
    const unsigned short* whp = Wh + (size_t)(bn + arow) * K + akq;
    const unsigned short* wlp = Wl + (size_t)(bn + arow) * K + akq;
    f32x4 acc[4][4];
    #pragma unroll
    for (int i = 0; i < 4; ++i)
        #pragma unroll
        for (int j = 0; j < 4; ++j) acc[i][j] = (f32x4){0.f, 0.f, 0.f, 0.f};
    for (int k0 = 0; k0 < K; k0 += 32) {
        short8v a0 = *(const short8v*)(ahp + k0);
        short8v a1 = *(const short8v*)(ahp + k0 + 8);
        short8v l0 = *(const short8v*)(alp + k0);
        short8v l1 = *(const short8v*)(alp + k0 + 8);
        short8v w0 = *(const short8v*)(whp + k0);
        short8v w1 = *(const short8v*)(whp + k0 + 8);
        short8v v0 = *(const short8v*)(wlp + k0);
        short8v v1 = *(const short8v*)(wlp + k0 + 8);
        __syncthreads();
        *(short8v*)&sAh[arow][akq] = a0; *(short8v*)&sAh[arow][akq + 8] = a1;
        *(short8v*)&sAl[arow][akq] = l0; *(short8v*)&sAl[arow][akq + 8] = l1;
        *(short8v*)&sWh[arow][akq] = w0; *(short8v*)&sWh[arow][akq + 8] = w1;
        *(short8v*)&sWl[arow][akq] = v0; *(short8v*)&sWl[arow][akq + 8] = v1;
        __syncthreads();
        short8v ah[4], al[4];
        #pragma unroll
        for (int mf = 0; mf < 4; ++mf) {
            ah[mf] = *(const short8v*)&sAh[wr + mf * 16 + lr][kg * 8];
            al[mf] = *(const short8v*)&sAl[wr + mf * 16 + lr][kg * 8];
        }
        #pragma unroll
        for (int nf = 0; nf < 4; ++nf) {
            short8v bh = *(const short8v*)&sWh[wc + nf * 16 + lr][kg * 8];
            short8v bl = *(const short8v*)&sWl[wc + nf * 16 + lr][kg * 8];
            #pragma unroll
            for (int mf = 0; mf < 4; ++mf) {
                acc[mf][nf] = __builtin_amdgcn_mfma_f32_16x16x32_bf16(ah[mf], bh, acc[mf][nf], 0, 0, 0);
                acc[mf][nf] = __builtin_amdgcn_mfma_f32_16x16x32_bf16(ah[mf], bl, acc[mf][nf], 0, 0, 0);
                acc[mf][nf] = __builtin_amdgcn_mfma_f32_16x16x32_bf16(al[mf], bh, acc[mf][nf], 0, 0, 0);
            }
        }
    }
    #pragma unroll
    for (int mf = 0; mf < 4; ++mf) {
        #pragma unroll
        for (int nf = 0; nf < 4; ++nf) {
            int colg = bn + wc + nf * 16 + lr;
            int ck = colg >> 4, cw = colg & 15;
            float bv = bias[colg];
            float* cbase = C + (size_t)ck * NPAD * 16 + cw;
            #pragma unroll
            for (int r = 0; r < 4; ++r) {
                int lrow = wr + mf * 16 + kg * 4 + r;
                if (bm + lrow < Mc) {
                    int grow = ridx[lrow];
                    float x = acc[mf][nf][r] + bv;
                    if (RELU) x = fmaxf(x, 0.f);
                    cbase[(size_t)grow * 16] = x;
                }
            }
        }
    }
}

// dec1 GEMM with fused input: reads A,B CHUNK-MAJOR, computes ((mask?A:0)+B)*rs,
// splits in-registers. C written row-major Nn=128 (agg_bias reads row-major).
__global__ __launch_bounds__(256, 3) void gemm_dec1_kernel(
    const float* __restrict__ A, const float* __restrict__ B,
    const float* __restrict__ mask, const float* __restrict__ rs,
    const unsigned short* __restrict__ Wh, const unsigned short* __restrict__ Wl,
    float* __restrict__ C, int M, int K, int NPAD) {
    __shared__ __align__(16) short sAh[128][40];
    __shared__ __align__(16) short sAl[128][40];
    __shared__ __align__(16) short sWh[128][40];
    __shared__ __align__(16) short sWl[128][40];
    const int Nn = 128;
    int tid = threadIdx.x;
    int bm = blockIdx.x * 128, bn = 0;
    int lane = tid & 63, wid = tid >> 6;
    int wr = (wid >> 1) * 64, wc = (wid & 1) * 64;
    int lr = lane & 15, kg = lane >> 4;
    int arow = tid >> 1, akq = (tid & 1) * 16;
    float mv = (mask[bm + arow] != 0.f) ? 1.f : 0.f;
    float rsv = rs[bm + arow];
    const unsigned short* whp = Wh + (size_t)(bn + arow) * K + akq;
    const unsigned short* wlp = Wl + (size_t)(bn + arow) * K + akq;
    f32x4 acc[4][4];
    #pragma unroll
    for (int i = 0; i < 4; ++i)
        #pragma unroll
        for (int j = 0; j < 4; ++j) acc[i][j] = (f32x4){0.f, 0.f, 0.f, 0.f};
    for (int k0 = 0; k0 < K; k0 += 32) {
        int ck = (k0 + akq) >> 4;   // chunk-major: 16-float slice = one chunk row
        const float4* pa = (const float4*)A + ((size_t)ck * NPAD + bm + arow) * 4;
        const float4* pb = (const float4*)B + ((size_t)ck * NPAD + bm + arow) * 4;
        float4 qa0 = pa[0], qa1 = pa[1], qa2 = pa[2], qa3 = pa[3];
        float4 qb0 = pb[0], qb1 = pb[1], qb2 = pb[2], qb3 = pb[3];
        ushort4 h0, l0v, h1, l1v, h2, l2v, h3, l3v;
        split4((qa0.x * mv + qb0.x) * rsv, (qa0.y * mv + qb0.y) * rsv,
               (qa0.z * mv + qb0.z) * rsv, (qa0.w * mv + qb0.w) * rsv, h0, l0v);
        split4((qa1.x * mv + qb1.x) * rsv, (qa1.y * mv + qb1.y) * rsv,
               (qa1.z * mv + qb1.z) * rsv, (qa1.w * mv + qb1.w) * rsv, h1, l1v);
        split4((qa2.x * mv + qb2.x) * rsv, (qa2.y * mv + qb2.y) * rsv,
               (qa2.z * mv + qb2.z) * rsv, (qa2.w * mv + qb2.w) * rsv, h2, l2v);
        split4((qa3.x * mv + qb3.x) * rsv, (qa3.y * mv + qb3.y) * rsv,
               (qa3.z * mv + qb3.z) * rsv, (qa3.w * mv + qb3.w) * rsv, h3, l3v);
        short8v w0 = *(const short8v*)(whp + k0);
        short8v w1 = *(const short8v*)(whp + k0 + 8);
        short8v v0 = *(const short8v*)(wlp + k0);
        short8v v1 = *(const short8v*)(wlp + k0 + 8);
        __syncthreads();
        *(ushort4*)&sAh[arow][akq]      = h0; *(ushort4*)&sAh[arow][akq + 4]  = h1;
        *(ushort4*)&sAh[arow][akq + 8]  = h2; *(ushort4*)&sAh[arow][akq + 12] = h3;
        *(ushort4*)&sAl[arow][akq]      = l0v; *(ushort4*)&sAl[arow][akq + 4]  = l1v;
        *(ushort4*)&sAl[arow][akq + 8]  = l2v; *(ushort4*)&sAl[arow][akq + 12] = l3v;
        *(short8v*)&sWh[arow][akq] = w0; *(short8v*)&sWh[arow][akq + 8] = w1;
        *(short8v*)&sWl[arow][akq] = v0; *(short8v*)&sWl[arow][akq + 8] = v1;
        __syncthreads();
        short8v ah[4], al[4];
        #pragma unroll
        for (int mf = 0; mf < 4; ++mf) {
            ah[mf] = *(const short8v*)&sAh[wr + mf * 16 + lr][kg * 8];
            al[mf] = *(const short8v*)&sAl[wr + mf * 16 + lr][kg * 8];
        }
        #pragma unroll
        for (int nf = 0; nf < 4; ++nf) {
            short8v bh = *(const short8v*)&sWh[wc + nf * 16 + lr][kg * 8];
            short8v bl = *(const short8v*)&sWl[wc + nf * 16 + lr][kg * 8];
            #pragma unroll
            for (int mf = 0; mf < 4; ++mf) {
                acc[mf][nf] = __builtin_amdgcn_mfma_f32_16x16x32_bf16(ah[mf], bh, acc[mf][nf], 0, 0, 0);
                acc[mf][nf] = __builtin_amdgcn_mfma_f32_16x16x32_bf16(ah[mf], bl, acc[mf][nf], 0, 0, 0);
                acc[mf][nf] = __builtin_amdgcn_mfma_f32_16x16x32_bf16(al[mf], bh, acc[mf][nf], 0, 0, 0);
            }
        }
    }
    #pragma unroll
    for (int mf = 0; mf < 4; ++mf) {
        #pragma unroll
        for (int nf = 0; nf < 4; ++nf) {
            int colg = bn + wc + nf * 16 + lr;
            #pragma unroll
            for (int r = 0; r < 4; ++r) {
                int grow = bm + wr + mf * 16 + kg * 4 + r;
                if (grow < M) C[(size_t)grow * Nn + colg] = acc[mf][nf][r];
            }
        }
    }
}

// ---------------- legacy vector GEMM (non-fast fallback only) ----------------
template <bool RELU>
__global__ __launch_bounds__(256) void gemm_kernel(const float* __restrict__ A,
                                                   const float* __restrict__ W,
                                                   const float* __restrict__ bias,
                                                   const float* __restrict__ mask,
                                                   const float* __restrict__ rowscale,
                                                   float* __restrict__ C, int M, int K, int Nn) {
    __shared__ float As[16][68];
    __shared__ float Bs[16][132];
    int tid = threadIdx.x;
    int bm = blockIdx.x * 64, bn = blockIdx.y * 128;
    int mA = tid >> 2, kqA = (tid & 3) * 4;
    int kB = tid >> 4, nqB = (tid & 15) * 8;
    int tm = (tid >> 4) * 4, tn = (tid & 15) * 4;
    float acc[4][8] = {};
    float rs = rowscale ? rowscale[bm + mA] : 1.f;
    for (int k0 = 0; k0 < K; k0 += 16) {
        float4 av = *(const float4*)(A + (size_t)(bm + mA) * K + k0 + kqA);
        As[kqA + 0][mA] = av.x * rs; As[kqA + 1][mA] = av.y * rs;
        As[kqA + 2][mA] = av.z * rs; As[kqA + 3][mA] = av.w * rs;
        const float* wp = W + (size_t)(k0 + kB) * Nn + bn + nqB;
        *(float4*)&Bs[kB][nqB]     = *(const float4*)wp;
        *(float4*)&Bs[kB][nqB + 4] = *(const float4*)(wp + 4);
        __syncthreads();
        #pragma unroll
        for (int kk = 0; kk < 16; ++kk) {
            float4 a  = *(const float4*)&As[kk][tm];
            float4 b0 = *(const float4*)&Bs[kk][tn];
            float4 b1 = *(const float4*)&Bs[kk][tn + 64];
            float ar[4] = {a.x, a.y, a.z, a.w};
            float br[8] = {b0.x, b0.y, b0.z, b0.w, b1.x, b1.y, b1.z, b1.w};
            #pragma unroll
            for (int i2 = 0; i2 < 4; i2++)
                #pragma unroll
                for (int j = 0; j < 8; j++) acc[i2][j] += ar[i2] * br[j];
        }
        __syncthreads();
    }
    #pragma unroll
    for (int i2 = 0; i2 < 4; i2++) {
        int row = bm + tm + i2;
        if (row < M) {
            float mv = mask ? mask[row] : 1.f;
            float o[8];
            #pragma unroll
            for (int j = 0; j < 8; j++) {
                int cj = (j < 4) ? (tn + j) : (64 + tn + j - 4);
                float x = acc[i2][j] + (bias ? bias[bn + cj] : 0.f);
                if (RELU) x = fmaxf(x, 0.f);
                o[j] = x * mv;
            }
            float* cp = C + (size_t)row * Nn + bn;
            *(float4*)(cp + tn)      = make_float4(o[0], o[1], o[2], o[3]);
            *(float4*)(cp + 64 + tn) = make_float4(o[4], o[5], o[6], o[7]);
        }
    }
}

// ---------------- pooling score (CM: chunk-major input) ----------------
template <bool CM>
__global__ void score_kernel(const float* __restrict__ H, const float* __restrict__ Wp,
                             const float* __restrict__ bp, const float* __restrict__ mask,
                             float* __restrict__ scores, float* __restrict__ keys,
                             int n, int NPAD) {
    int lane = threadIdx.x & 63;
    int node = blockIdx.x * 4 + (threadIdx.x >> 6);
    if (node >= n) return;
    float4 hv;
    if (CM) {
        int c = lane >> 2, q = lane & 3;
        hv = ((const float4*)H)[((size_t)c * NPAD + node) * 4 + q];
    } else {
        hv = ((const float4*)(H + (size_t)node * 256))[lane];
    }
    float4 wq = ((const float4*)Wp)[lane];
    float d = hv.x * wq.x + hv.y * wq.y + hv.z * wq.z + hv.w * wq.w;
    #pragma unroll
    for (int off = 32; off > 0; off >>= 1) d += __shfl_down(d, off);
    if (lane == 0) {
        float sc = 1.f / (1.f + expf(-(d + bp[0])));
        scores[node] = sc;
        keys[node] = (mask && mask[node] == 0.f) ? -1e9f : sc;
    }
}

// ---------------- top-K selection ----------------
__device__ __forceinline__ unsigned key_u(float f) {
    unsigned u = __float_as_uint(f);
    return (u & 0x80000000u) ? ~u : (u | 0x80000000u);
}

__device__ __forceinline__ void wave_hist_add(int* __restrict__ hist, unsigned bin, bool valid) {
    int lane = threadIdx.x & 63;
    while (true) {
        unsigned long long vmask = __ballot(valid);
        if (vmask == 0ull) break;
        int leader = __ffsll((long long)vmask) - 1;
        unsigned lbin = (unsigned)__shfl((int)bin, leader);
        bool match = valid && (bin == lbin);
        unsigned long long mmask = __ballot(match);
        if (lane == leader) atomicAdd(&hist[lbin], __popcll(mmask));
        if (match) valid = false;
    }
}

// -------- fallback: single block radix select --------
__global__ void topk_kernel(const float* __restrict__ keys, const float* __restrict__ scores,
                            float* __restrict__ nm, float* __restrict__ gate, int n, int K) {
    __shared__ int hist[256];
    __shared__ unsigned sh_prefix;
    __shared__ int sh_krem;
    __shared__ int sh_running;
    __shared__ int wsum[16];
    int tid = threadIdx.x, lane = tid & 63, wid = tid >> 6;
    if (tid == 0) { sh_prefix = 0u; sh_krem = K; sh_running = 0; }
    __syncthreads();
    for (int pass = 0; pass < 4; ++pass) {
        int shift = 24 - pass * 8;
        if (tid < 256) hist[tid] = 0;
        __syncthreads();
        unsigned pmask = (pass == 0) ? 0u : (0xFFFFFFFFu << (shift + 8));
        unsigned prefix = sh_prefix;
        for (int i = tid; i < n; i += 1024) {
            unsigned u = key_u(keys[i]);
            if ((u & pmask) == prefix) atomicAdd(&hist[(u >> shift) & 0xFF], 1);
        }
        __syncthreads();
        if (tid == 0) {
            int krem = sh_krem;
            int b;
            for (b = 255; b > 0; --b) {
                int c = hist[b];
                if (c >= krem) break;
                krem -= c;
            }
            sh_prefix = prefix | ((unsigned)b << shift);
            sh_krem = krem;
        }
        __syncthreads();
    }
    unsigned Tkey = sh_prefix;
    int need_eq = sh_krem;
    for (int base = 0; base < n; base += 1024) {
        int i = base + tid;
        unsigned u = 0; int flagv = 0;
        if (i < n) { u = key_u(keys[i]); flagv = (u == Tkey) ? 1 : 0; }
        unsigned long long bal = __ballot(flagv);
        int rank_w = __popcll(bal & ((1ull << lane) - 1ull));
        if (lane == 63) wsum[wid] = __popcll(bal);
        __syncthreads();
        int woff = 0;
        for (int w = 0; w < wid; ++w) woff += wsum[w];
        int grank = sh_running + woff + rank_w;
        if (i < n) {
            float v = (u > Tkey) ? 1.f : ((flagv && grank < need_eq) ? 1.f : 0.f);
            nm[i] = v;
            gate[i] = v * scores[i];
        }
        __syncthreads();
        if (tid == 0) {
            int tot = 0;
            for (int w = 0; w < 16; ++w) tot += wsum[w];
            sh_running += tot;
        }
        __syncthreads();
    }
}

// -------- fast path: grid-wide radix select, 2 passes of 16 bits --------
__global__ void topk_hist1(const float* __restrict__ keys, int n, int* __restrict__ hist) {
    int i = blockIdx.x * blockDim.x + threadIdx.x;
    unsigned bin = 0; bool valid = (i < n);
    if (valid) bin = key_u(keys[i]) >> 16;
    wave_hist_add(hist, bin, valid);
}

__global__ void topk_scan1(const int* __restrict__ hist, int K, int* __restrict__ sel) {
    __shared__ int arr[1024];
    int tid = threadIdx.x;
    int base = tid * 64;
    int local = 0;
    #pragma unroll 8
    for (int b = 0; b < 64; ++b) local += hist[base + b];
    arr[tid] = local;
    __syncthreads();
    for (int off = 1; off < 1024; off <<= 1) {
        int v = (tid + off < 1024) ? arr[tid + off] : 0;
        __syncthreads();
        arr[tid] += v;
        __syncthreads();
    }
    int above = arr[tid] - local;
    if (above < K && arr[tid] >= K) {
        int run = above;
        for (int b = base + 63; b >= base; --b) {
            int c = hist[b];
            if (run + c >= K) { sel[0] = b; sel[1] = K - run; break; }
            run += c;
        }
    }
}

__global__ void topk_hist2(const float* __restrict__ keys, int n, const int* __restrict__ sel,
                           int* __restrict__ hist) {
    int i = blockIdx.x * blockDim.x + threadIdx.x;
    unsigned bin = 0; bool valid = false;
    if (i < n) {
        unsigned u = key_u(keys[i]);
        if ((int)(u >> 16) == sel[0]) { bin = u & 0xFFFF; valid = true; }
    }
    wave_hist_add(hist, bin, valid);
}

__global__ void topk_scan2(const int* __restrict__ hist, int* __restrict__ sel,
                           int* __restrict__ tie_cnt) {
    __shared__ int arr[1024];
    int tid = threadIdx.x;
    if (tid == 0) *tie_cnt = 0;
    int K = sel[1];
    int base = tid * 64;
    int local = 0;
    #pragma unroll 8
    for (int b = 0; b < 64; ++b) local += hist[base + b];
    arr[tid] = local;
    __syncthreads();
    for (int off = 1; off < 1024; off <<= 1) {
        int v = (tid + off < 1024) ? arr[tid + off] : 0;
        __syncthreads();
        arr[tid] += v;
        __syncthreads();
    }
    int above = arr[tid] - local;
    if (above < K && arr[tid] >= K) {
        int run = above;
        for (int b = base + 63; b >= base; --b) {
            int c = hist[b];
            if (run + c >= K) {
                sel[2] = (int)((((unsigned)sel[0]) << 16) | (unsigned)b);
                sel[3] = K - run;
                break;
            }
            run += c;
        }
    }
}

__global__ void topk_mark(const float* __restrict__ keys, const float* __restrict__ scores,
                          const int* __restrict__ sel, float* __restrict__ nm,
                          float* __restrict__ gate, int* __restrict__ tie_list,
                          int* __restrict__ tie_cnt, int n) {
    int i = blockIdx.x * blockDim.x + threadIdx.x;
    if (i >= n) return;
    unsigned Tkey = (unsigned)sel[2];
    unsigned u = key_u(keys[i]);
    float v = 0.f;
    if (u > Tkey) v = 1.f;
    else if (u == Tkey) { int p = atomicAdd(tie_cnt, 1); tie_list[p] = i; }
    nm[i] = v;
    gate[i] = v * scores[i];
}

__global__ void topk_ties(const float* __restrict__ scores, const int* __restrict__ sel,
                          const int* __restrict__ tie_list, const int* __restrict__ tie_cnt,
                          float* __restrict__ nm, float* __restrict__ gate) {
    int cnt = *tie_cnt;
    int need = sel[3];
    for (int j = threadIdx.x; j < cnt; j += blockDim.x) {
        int idx = tie_list[j];
        int rank = 0;
        for (int k2 = 0; k2 < cnt; ++k2) rank += (tie_list[k2] < idx) ? 1 : 0;
        if (rank < need) { nm[idx] = 1.f; gate[idx] = scores[idx]; }
    }
}

// ---------------- selected-row compaction (order-independent) ----------------
__global__ void compact_kernel(const float* __restrict__ nm, int* __restrict__ idx,
                               int* __restrict__ cnt, int n) {
    int i = blockIdx.x * blockDim.x + threadIdx.x;
    if (i < n && nm[i] != 0.f) {
        int p = atomicAdd(cnt, 1);
        idx[p] = i;
    }
}

// ---------------- adds ----------------
__global__ void add_mask_kernel(float* __restrict__ A, const float* __restrict__ B,
                                const float* __restrict__ mask, int n4) {
    int i = blockIdx.x * blockDim.x + threadIdx.x;
    if (i < n4) {
        float4 a = ((float4*)A)[i];
        float4 b = ((const float4*)B)[i];
        if (mask && mask[i >> 6] == 0.f) { a.x = 0.f; a.y = 0.f; a.z = 0.f; a.w = 0.f; }
        a.x += b.x; a.y += b.y; a.z += b.z; a.w += b.w;
        ((float4*)A)[i] = a;
    }
}

// chunk-major variant: A,B laid out [16][NPAD][16]; mask indexed by node
__global__ void add_mask_cm_kernel(float* __restrict__ A, const float* __restrict__ B,
                                   const float* __restrict__ mask, int n, int NPAD) {
    int i = blockIdx.x * blockDim.x + threadIdx.x;
    int per = n * 4;                 // float4s per chunk
    int total = 16 * per;
    if (i >= total) return;
    int c = i / per;
    int w = i - c * per;
    int node = w >> 2;
    size_t a4 = (size_t)c * NPAD * 4 + w;
    float4 a = ((float4*)A)[a4];
    float4 b = ((const float4*)B)[a4];
    if (mask[node] == 0.f) { a.x = 0.f; a.y = 0.f; a.z = 0.f; a.w = 0.f; }
    a.x += b.x; a.y += b.y; a.z += b.z; a.w += b.w;
    ((float4*)A)[a4] = a;
}

extern "C" void kernel_launch(void* const* d_in, const int* in_sizes, int n_in,
                              void* d_out, int out_size, void* d_ws, size_t ws_size,
                              hipStream_t stream) {
    const int n = in_sizes[0] / 128;   // 50000
    const int E = in_sizes[1];         // 800000
    const int NPAD = ((n + 127) / 128) * 128;   // 128-divisible for MFMA tiles
    const int K1 = 25000, K2 = 12500;

    const float* features = (const float*)d_in[0];
    const int* src = (const int*)d_in[1];
    const int* dst = (const int*)d_in[2];
    const float* W_embed = (const float*)d_in[3];
    const float* b_embed = (const float*)d_in[4];
    const float* W_enc0  = (const float*)d_in[5];
    const float* b_enc0  = (const float*)d_in[6];
    const float* W_enc1  = (const float*)d_in[7];
    const float* b_enc1  = (const float*)d_in[8];
    const float* W_p0    = (const float*)d_in[9];
    const float* b_p0    = (const float*)d_in[10];
    const float* W_p1    = (const float*)d_in[11];
    const float* b_p1    = (const float*)d_in[12];
    const float* W_bot   = (const float*)d_in[13];
    const float* b_bot   = (const float*)d_in[14];
    const float* W_dec0  = (const float*)d_in[15];
    const float* b_dec0  = (const float*)d_in[16];
    const float* W_dec1  = (const float*)d_in[17];
    const float* b_dec1  = (const float*)d_in[18];
    float* out_f = (float*)d_out;

    char* ws = (char*)d_ws;
    size_t off = 0;
    auto alloc = [&](size_t bytes) -> void* {
        void* p = ws + off;
        off += (bytes + 255) & ~(size_t)255;
        return p;
    };
    (void)alloc(256);  // pad (R2 'flag' slot)
    int* row_ptr  = (int*)alloc((size_t)(n + 1) * 4);
    int* cursor   = (int*)alloc((size_t)n * 4);
    int* col      = (int*)alloc((size_t)E * 4);
    int* deg_out_i= (int*)alloc((size_t)n * 4);
    int* deg_in_i = (int*)alloc((size_t)n * 4);
    float* so_m1  = (float*)alloc((size_t)n * 4);
    float* si_m1  = (float*)alloc((size_t)n * 4);
    float* so_m2  = (float*)alloc((size_t)n * 4);
    float* si_m2  = (float*)alloc((size_t)n * 4);
    float* sarr   = (float*)alloc((size_t)n * 4);
    float* tarr   = (float*)alloc((size_t)n * 4);
    float* scores1= (float*)alloc((size_t)n * 4);
    float* keys1  = (float*)alloc((size_t)n * 4);
    float* scores2= (float*)alloc((size_t)n * 4);
    float* keys2  = (float*)alloc((size_t)n * 4);
    float* nm1    = (float*)alloc((size_t)n * 4);
    float* gate1  = (float*)alloc((size_t)n * 4);
    float* nm2    = (float*)alloc((size_t)n * 4);
    float* gate2  = (float*)alloc((size_t)n * 4);
    size_t big = (size_t)NPAD * 256 * 4;
    float* A = (float*)alloc(big);     // fast path: CHUNK-MAJOR [16][NPAD][16]
    float* B = (float*)alloc(big);     // chunk-major
    float* C = (float*)alloc(big);     // chunk-major (dec1 output: row-major 128)
    float* D = (float*)alloc(big);     // split hi/lo planes (row-major bf16)
    unsigned short* Dh = (unsigned short*)D;
    unsigned short* Dl = Dh + (size_t)NPAD * 256;
    unsigned short* Dh128 = Dh;
    unsigned short* Dl128 = Dh + (size_t)NPAD * 128;
    // ---- tail ----
    int* rhist    = (int*)alloc(65536 * 4);
    int* sel      = (int*)alloc(256);
    int* tie_cnt  = (int*)alloc(256);
    int* tie_list = (int*)alloc((size_t)n * 4);
    float* s0     = (float*)alloc((size_t)n * 4);
    float* t0     = (float*)alloc((size_t)n * 4);
    int* idx1     = (int*)alloc((size_t)n * 4);
    int* idx2     = (int*)alloc((size_t)n * 4);
    int* ccnt     = (int*)alloc(256);
    // split-bf16 transposed weight planes: 327680 elems total
    const int WO_EMBED = 0, WO_ENC0 = 32768, WO_ENC1 = 98304,
              WO_BOT = 163840, WO_DEC0 = 229376, WO_DEC1 = 294912;
    const int WTOT = 327680;
    unsigned short* wsph = (unsigned short*)alloc((size_t)WTOT * 2);
    unsigned short* wspl = (unsigned short*)alloc((size_t)WTOT * 2);
    bool fast = (off <= ws_size);

    dim3 blk(256);
    int gE = (E + 255) / 256;
    int gN = (n + 255) / 256;
    int Gcm = (n + 63) / 64;               // node groups for cm agg (64 nodes/block)
    int gAggCM = 2 * Gcm * 8;              // [phase 2][group][8 xcd chunks]
    int gAgg256 = (n + 3) / 4;             // fallback row-major agg
    int gAgg128 = (n + 7) / 8;
    int gScore = (n + 3) / 4;
    dim3 gemm_g(NPAD / 128, 2);            // MFMA 128x128 tiles, Nn=256
    dim3 gemm_g128(NPAD / 128, 1);         // Nn=128 (dec1)
    dim3 gemm_gK1((K1 + 127) / 128, 2);
    dim3 gemm_gK2((K2 + 127) / 128, 2);
    dim3 gemm_gv(NPAD / 64, 2);            // legacy vector GEMM grids (fallback)
    dim3 gemm_gv128(NPAD / 64, 1);
    int gAdd = (n * 64 + 255) / 256;
    int gAddCM = (16 * n * 4 + 255) / 256;

    auto run_topk = [&](const float* keys, const float* scores, float* nm, float* gate, int K) {
        if (fast) {
            hipMemsetAsync(rhist, 0, 65536 * 4, stream);
            topk_hist1<<<gN, blk, 0, stream>>>(keys, n, rhist);
            topk_scan1<<<1, 1024, 0, stream>>>(rhist, K, sel);
            hipMemsetAsync(rhist, 0, 65536 * 4, stream);
            topk_hist2<<<gN, blk, 0, stream>>>(keys, n, sel, rhist);
            topk_scan2<<<1, 1024, 0, stream>>>(rhist, sel, tie_cnt);
            topk_mark<<<gN, blk, 0, stream>>>(keys, scores, sel, nm, gate, tie_list, tie_cnt, n);
            topk_ties<<<1, 256, 0, stream>>>(scores, sel, tie_list, tie_cnt, nm, gate);
        } else {
            topk_kernel<<<1, 1024, 0, stream>>>(keys, scores, nm, gate, n, K);
        }
    };
    float* sF = fast ? s0 : sarr;
    float* tF = fast ? t0 : tarr;

    // ---- weight split/transpose (once per forward; independent of CSR) ----
    if (fast) {
        wsplit_all_kernel<<<WTOT / 256, blk, 0, stream>>>(W_embed, W_enc0, W_enc1, W_bot,
                                                          W_dec0, W_dec1, wsph, wspl);
    }

    // ---- CSR build ----
    {   // deg_out_i and deg_in_i are consecutive allocations: one memset covers both
        size_t degpad = (((size_t)n * 4) + 255) & ~(size_t)255;
        hipMemsetAsync(deg_out_i, 0, degpad + (size_t)n * 4, stream);
    }
    hist_kernel<<<gE, blk, 0, stream>>>(src, dst, deg_out_i, deg_in_i, E);
    scan_kernel<<<1, 1024, 0, stream>>>(deg_in_i, row_ptr, cursor, n);
    fill_kernel<<<gE, blk, 0, stream>>>(src, dst, cursor, col, E);
    sort_rows_kernel<<<gN, blk, 0, stream>>>(row_ptr, col, n);

    // ---- full-graph degree scales (once) ----
    scale_full_kernel<<<gN, blk, 0, stream>>>(deg_out_i, deg_in_i, sF, tF, n);

    // ---- embed GCN (full graph) -> A (cm) ----
    if (fast) {
        agg_feat_128_kernel<true><<<gAgg128, blk, 0, stream>>>(row_ptr, col, features, sF, tF,
                                                               nullptr, Dh128, Dl128, n);
        gemm_mfma_kernel<true><<<gemm_g, blk, 0, stream>>>(Dh128, Dl128, wsph + WO_EMBED,
                                                           wspl + WO_EMBED, b_embed, A, n, 128, NPAD);
    } else {
        agg_feat_128_kernel<false><<<gAgg128, blk, 0, stream>>>(row_ptr, col, features, sF, tF,
                                                                D, nullptr, nullptr, n);
        gemm_kernel<true><<<gemm_gv, blk, 0, stream>>>(D, W_embed, b_embed, nullptr, nullptr, A, n, 128, 256);
    }

    // ---- enc0 (full graph); hidden0 = B (cm) ----
    if (fast) {
        agg_cm_256_kernel<false><<<gAggCM, blk, 0, stream>>>(row_ptr, col, A, sF, tF,
                                                             Dh, Dl, n, NPAD, Gcm);
        gemm_mfma_kernel<true><<<gemm_g, blk, 0, stream>>>(Dh, Dl, wsph + WO_ENC0, wspl + WO_ENC0,
                                                           b_enc0, B, n, 256, NPAD);
    } else {
        agg_f32_256_kernel<false, false><<<gAgg256, blk, 0, stream>>>(row_ptr, col, A, sF, tF,
                                                                      D, nullptr, nullptr, n);
        gemm_kernel<true><<<gemm_gv, blk, 0, stream>>>(D, W_enc0, b_enc0, nullptr, nullptr, B, n, 256, 256);
    }

    // ---- pool0 ----
    if (fast)
        score_kernel<true><<<gScore, blk, 0, stream>>>(B, W_p0, b_p0, nullptr, scores1, keys1, n, NPAD);
    else
        score_kernel<false><<<gScore, blk, 0, stream>>>(B, W_p0, b_p0, nullptr, scores1, keys1, n, NPAD);
    run_topk(keys1, scores1, nm1, gate1, K1);
    if (fast) {
        hipMemsetAsync(ccnt, 0, 4, stream);
        compact_kernel<<<gN, blk, 0, stream>>>(nm1, idx1, ccnt, n);
    }

    // ---- enc1 (mask m1, gated input); hidden1 = C (cm) ----
    hipMemsetAsync(so_m1, 0, (size_t)n * 4, stream);
    out_deg_mask_kernel<<<gE, blk, 0, stream>>>(src, dst, nm1, so_m1, E);
    in_deg_mask_kernel<<<gN, blk, 0, stream>>>(row_ptr, col, nm1, si_m1, n);
    scale_mask_kernel<<<gN, blk, 0, stream>>>(gate1, nm1, so_m1, si_m1, sarr, tarr, n);
    if (fast) {
        agg_cm_256_kernel<true><<<gAggCM, blk, 0, stream>>>(row_ptr, col, B, sarr, tarr,
                                                            Dh, Dl, n, NPAD, Gcm);
        gemm_rows_mfma_kernel<true><<<gemm_gK1, blk, 0, stream>>>(Dh, Dl, wsph + WO_ENC1,
                                                                  wspl + WO_ENC1, b_enc1, idx1, K1, C, 256, NPAD);
    } else {
        agg_f32_256_kernel<true, false><<<gAgg256, blk, 0, stream>>>(row_ptr, col, B, sarr, tarr,
                                                                     D, nullptr, nullptr, n);
        gemm_kernel<true><<<gemm_gv, blk, 0, stream>>>(D, W_enc1, b_enc1, nm1, nullptr, C, n, 256, 256);
    }

    // ---- pool1 ----
    if (fast)
        score_kernel<true><<<gScore, blk, 0, stream>>>(C, W_p1, b_p1, nm1, scores2, keys2, n, NPAD);
    else
        score_kernel<false><<<gScore, blk, 0, stream>>>(C, W_p1, b_p1, nm1, scores2, keys2, n, NPAD);
    run_topk(keys2, scores2, nm2, gate2, K2);
    if (fast) {
        hipMemsetAsync(ccnt + 1, 0, 4, stream);
        compact_kernel<<<gN, blk, 0, stream>>>(nm2, idx2, ccnt + 1, n);
    }

    // ---- bottleneck (mask m2, gated input) -> A (cm) ----
    hipMemsetAsync(so_m2, 0, (size_t)n * 4, stream);
    out_deg_mask_kernel<<<gE, blk, 0, stream>>>(src, dst, nm2, so_m2, E);
    in_deg_mask_kernel<<<gN, blk, 0, stream>>>(row_ptr, col, nm2, si_m2, n);
    scale_mask_kernel<<<gN, blk, 0, stream>>>(gate2, nm2, so_m2, si_m2, sarr, tarr, n);
    if (fast) {
        agg_cm_256_kernel<true><<<gAggCM, blk, 0, stream>>>(row_ptr, col, C, sarr, tarr,
                                                            Dh, Dl, n, NPAD, Gcm);
        gemm_rows_mfma_kernel<true><<<gemm_gK2, blk, 0, stream>>>(Dh, Dl, wsph + WO_BOT,
                                                                  wspl + WO_BOT, b_bot, idx2, K2, A, 256, NPAD);
    } else {
        agg_f32_256_kernel<true, false><<<gAgg256, blk, 0, stream>>>(row_ptr, col, C, sarr, tarr,
                                                                     D, nullptr, nullptr, n);
        gemm_kernel<true><<<gemm_gv, blk, 0, stream>>>(D, W_bot, b_bot, nm2, nullptr, A, n, 256, 256);
    }

    // ---- dec0: h = (m2? bot : 0) + hidden1, GCN mask m1 -> A (cm) ----
    if (fast)
        add_mask_cm_kernel<<<gAddCM, blk, 0, stream>>>(A, C, nm2, n, NPAD);
    else
        add_mask_kernel<<<gAdd, blk, 0, stream>>>(A, C, nullptr, n * 64);
    scale_mask_kernel<<<gN, blk, 0, stream>>>(nm1, nm1, so_m1, si_m1, sarr, tarr, n);
    if (fast) {
        agg_cm_256_kernel<true><<<gAggCM, blk, 0, stream>>>(row_ptr, col, A, sarr, tarr,
                                                            Dh, Dl, n, NPAD, Gcm);
        gemm_rows_mfma_kernel<true><<<gemm_gK1, blk, 0, stream>>>(Dh, Dl, wsph + WO_DEC0,
                                                                  wspl + WO_DEC0, b_dec0, idx1, K1, A, 256, NPAD);
    } else {
        agg_f32_256_kernel<true, false><<<gAgg256, blk, 0, stream>>>(row_ptr, col, A, sarr, tarr,
                                                                     D, nullptr, nullptr, n);
        gemm_kernel<true><<<gemm_gv, blk, 0, stream>>>(D, W_dec0, b_dec0, nm1, nullptr, A, n, 256, 256);
    }

    // ---- dec1 (reordered, final layer): h = (m1? dec0 : 0) + hidden0;
    //      P = (s0 .* h) @ W_dec1 -> C (row-major 128);  out = t0*agg(P) + b ----
    if (fast) {
        gemm_dec1_kernel<<<gemm_g128, blk, 0, stream>>>(A, B, nm1, sF, wsph + WO_DEC1,
                                                        wspl + WO_DEC1, C, n, 256, NPAD);
    } else {
        add_mask_kernel<<<gAdd, blk, 0, stream>>>(A, B, nullptr, n * 64);
        scale_full_kernel<<<gN, blk, 0, stream>>>(deg_out_i, deg_in_i, sarr, tarr, n);
        gemm_kernel<false><<<gemm_gv128, blk, 0, stream>>>(A, W_dec1, nullptr, nullptr, sF, C, n, 256, 128);
    }
    agg_bias_128_kernel<<<gAgg128, blk, 0, stream>>>(row_ptr, col, C, tF, b_dec1, out_f, n);

    (void)n_in; (void)out_size;
}

// Round 7
// 1131.881 us; speedup vs baseline: 1.4156x; 1.4156x over previous
//
#include <hip/hip_runtime.h>
#include <hip/hip_bf16.h>
#include <type_traits>

// ---------------- CSR build ----------------
__global__ void hist_kernel(const int* __restrict__ src, const int* __restrict__ dst,
                            int* __restrict__ deg_out, int* __restrict__ deg_in, int E) {
    int e = blockIdx.x * blockDim.x + threadIdx.x;
    if (e < E) {
        atomicAdd(&deg_out[src[e]], 1);
        atomicAdd(&deg_in[dst[e]], 1);
    }
}

__global__ void scan_kernel(const int* __restrict__ deg, int* __restrict__ row_ptr,
                            int* __restrict__ cursor, int n) {
    __shared__ int wsum[16];
    __shared__ int running;
    int tid = threadIdx.x, lane = tid & 63, wid = tid >> 6;
    if (tid == 0) running = 0;
    __syncthreads();
    for (int base = 0; base < n; base += 1024) {
        int i = base + tid;
        int v = (i < n) ? deg[i] : 0;
        int incl = v;
        #pragma unroll
        for (int off = 1; off < 64; off <<= 1) {
            int t = __shfl_up(incl, off);
            if (lane >= off) incl += t;
        }
        if (lane == 63) wsum[wid] = incl;
        __syncthreads();
        if (wid == 0 && lane < 16) {
            int s = wsum[lane], si = s;
            #pragma unroll
            for (int off = 1; off < 16; off <<= 1) {
                int t = __shfl_up(si, off);
                if (lane >= off) si += t;
            }
            wsum[lane] = si - s;  // exclusive
        }
        __syncthreads();
        int excl = running + wsum[wid] + (incl - v);
        if (i < n) { row_ptr[i] = excl; cursor[i] = excl; }
        __syncthreads();
        if (tid == 1023) running = excl + v;
        __syncthreads();
    }
    if (tid == 0) row_ptr[n] = running;
}

__global__ void fill_kernel(const int* __restrict__ src, const int* __restrict__ dst,
                            int* __restrict__ cursor, int* __restrict__ col, int E) {
    int e = blockIdx.x * blockDim.x + threadIdx.x;
    if (e < E) {
        int p = atomicAdd(&cursor[dst[e]], 1);
        col[p] = src[e];
    }
}

// deterministic neighbor order: insertion-sort each CSR row (avg deg 16)
__global__ void sort_rows_kernel(const int* __restrict__ row_ptr, int* __restrict__ col, int n) {
    int v = blockIdx.x * blockDim.x + threadIdx.x;
    if (v >= n) return;
    int e0 = row_ptr[v], e1 = row_ptr[v + 1];
    for (int i = e0 + 1; i < e1; ++i) {
        int key = col[i];
        int j = i - 1;
        while (j >= e0 && col[j] > key) { col[j + 1] = col[j]; --j; }
        col[j + 1] = key;
    }
}

// ---------------- masked degrees ----------------
__global__ void out_deg_mask_kernel(const int* __restrict__ src, const int* __restrict__ dst,
                                    const float* __restrict__ m, float* __restrict__ so, int E) {
    int e = blockIdx.x * blockDim.x + threadIdx.x;
    if (e < E) {
        float md = m[dst[e]];
        if (md != 0.f) atomicAdd(&so[src[e]], md);
    }
}

__global__ void in_deg_mask_kernel(const int* __restrict__ row_ptr, const int* __restrict__ col,
                                   const float* __restrict__ m, float* __restrict__ si, int n) {
    int v = blockIdx.x * blockDim.x + threadIdx.x;
    if (v < n) {
        float s = 0.f;
        int e1 = row_ptr[v + 1];
        for (int e = row_ptr[v]; e < e1; ++e) s += m[col[e]];
        si[v] = s;
    }
}

__global__ void scale_full_kernel(const int* __restrict__ dout, const int* __restrict__ din,
                                  float* __restrict__ s, float* __restrict__ t, int n) {
    int v = blockIdx.x * blockDim.x + threadIdx.x;
    if (v < n) {
        s[v] = 1.f / sqrtf((float)max(dout[v], 1));
        t[v] = 1.f / sqrtf((float)max(din[v], 1));
    }
}

__global__ void scale_mask_kernel(const float* __restrict__ gate, const float* __restrict__ mask,
                                  const float* __restrict__ so, const float* __restrict__ si,
                                  float* __restrict__ s, float* __restrict__ t, int n) {
    int v = blockIdx.x * blockDim.x + threadIdx.x;
    if (v < n) {
        s[v] = gate[v] * (1.f / sqrtf(fmaxf(so[v], 1.f)));
        t[v] = mask[v] * (1.f / sqrtf(fmaxf(si[v], 1.f)));
    }
}

// ---------------- split-bf16 helpers ----------------
__device__ __forceinline__ unsigned short f2bf(float x) {
    unsigned u = __float_as_uint(x);
    unsigned r = u + 0x7fffu + ((u >> 16) & 1u);   // RNE
    return (unsigned short)(r >> 16);
}
__device__ __forceinline__ float bf2f(unsigned short h) {
    return __uint_as_float(((unsigned)h) << 16);
}
__device__ __forceinline__ void split4(float x, float y, float z, float w,
                                       ushort4& hv, ushort4& lv) {
    hv.x = f2bf(x); lv.x = f2bf(x - bf2f(hv.x));
    hv.y = f2bf(y); lv.y = f2bf(y - bf2f(hv.y));
    hv.z = f2bf(z); lv.z = f2bf(z - bf2f(hv.z));
    hv.w = f2bf(w); lv.w = f2bf(w - bf2f(hv.w));
}

typedef __attribute__((ext_vector_type(8))) short short8v;
typedef __attribute__((ext_vector_type(4))) float f32x4;

// ---------------- aggregation from f32 FEATURES, F=128 (full graph) ----------------
template <bool SPLIT>
__global__ void agg_feat_128_kernel(const int* __restrict__ row_ptr, const int* __restrict__ col,
                                    const float* __restrict__ X, const float* __restrict__ s,
                                    const float* __restrict__ t, float* __restrict__ out,
                                    unsigned short* __restrict__ oh, unsigned short* __restrict__ ol,
                                    int n) {
    int tid = threadIdx.x;
    int node = blockIdx.x * 8 + (tid >> 5);
    int f4 = tid & 31;
    if (node >= n) return;
    int e0 = row_ptr[node], e1 = row_ptr[node + 1];
    const float4* X4 = (const float4*)X;
    float ax = 0.f, ay = 0.f, az = 0.f, aw = 0.f;
    int e = e0;
    for (; e + 3 < e1; e += 4) {
        int u0 = col[e], u1 = col[e + 1], u2 = col[e + 2], u3 = col[e + 3];
        float s0 = s[u0], s1 = s[u1], s2 = s[u2], s3 = s[u3];
        float4 x0 = X4[(size_t)u0 * 32 + f4];
        float4 x1 = X4[(size_t)u1 * 32 + f4];
        float4 x2 = X4[(size_t)u2 * 32 + f4];
        float4 x3 = X4[(size_t)u3 * 32 + f4];
        ax += s0 * x0.x; ay += s0 * x0.y; az += s0 * x0.z; aw += s0 * x0.w;
        ax += s1 * x1.x; ay += s1 * x1.y; az += s1 * x1.z; aw += s1 * x1.w;
        ax += s2 * x2.x; ay += s2 * x2.y; az += s2 * x2.z; aw += s2 * x2.w;
        ax += s3 * x3.x; ay += s3 * x3.y; az += s3 * x3.z; aw += s3 * x3.w;
    }
    for (; e < e1; ++e) {
        int u = col[e];
        float sc = s[u];
        float4 q = X4[(size_t)u * 32 + f4];
        ax += sc * q.x; ay += sc * q.y; az += sc * q.z; aw += sc * q.w;
    }
    float tv = t[node];
    if (SPLIT) {
        ushort4 hv, lv;
        split4(ax * tv, ay * tv, az * tv, aw * tv, hv, lv);
        *(ushort4*)&oh[(size_t)node * 128 + f4 * 4] = hv;
        *(ushort4*)&ol[(size_t)node * 128 + f4 * 4] = lv;
    } else {
        float4 r; r.x = ax * tv; r.y = ay * tv; r.z = az * tv; r.w = aw * tv;
        ((float4*)out)[(size_t)node * 32 + f4] = r;
    }
}

// ---------------- aggregation over f32 workspace, F=256 ----------------
// R19: edge loop unrolled 8 (was 4) — doubles in-flight gather transactions
// per wave (latency hiding). Per-edge sequential accumulation order kept
// identical to the unroll-4 version -> bit-identical results.
template <bool MASKED, bool SPLIT>
__global__ void agg_f32_256_kernel(const int* __restrict__ row_ptr, const int* __restrict__ col,
                                   const float* __restrict__ X, const float* __restrict__ s,
                                   const float* __restrict__ t, float* __restrict__ out,
                                   unsigned short* __restrict__ oh, unsigned short* __restrict__ ol,
                                   int n) {
    int tid = threadIdx.x;
    int node = blockIdx.x * 4 + (tid >> 6);
    int f4 = tid & 63;
    if (node >= n) return;
    float tv = t[node];
    if (MASKED && tv == 0.f) return;
    int e0 = row_ptr[node], e1 = row_ptr[node + 1];
    const float4* X4 = (const float4*)X;
    float ax = 0.f, ay = 0.f, az = 0.f, aw = 0.f;
    int e = e0;
    for (; e + 7 < e1; e += 8) {
        int u0 = col[e],     u1 = col[e + 1], u2 = col[e + 2], u3 = col[e + 3];
        int u4 = col[e + 4], u5 = col[e + 5], u6 = col[e + 6], u7 = col[e + 7];
        float s0 = s[u0], s1 = s[u1], s2 = s[u2], s3 = s[u3];
        float s4 = s[u4], s5 = s[u5], s6 = s[u6], s7 = s[u7];
        if (!MASKED) {
            float4 x0 = X4[(size_t)u0 * 64 + f4];
            float4 x1 = X4[(size_t)u1 * 64 + f4];
            float4 x2 = X4[(size_t)u2 * 64 + f4];
            float4 x3 = X4[(size_t)u3 * 64 + f4];
            float4 x4 = X4[(size_t)u4 * 64 + f4];
            float4 x5 = X4[(size_t)u5 * 64 + f4];
            float4 x6 = X4[(size_t)u6 * 64 + f4];
            float4 x7 = X4[(size_t)u7 * 64 + f4];
            ax += s0 * x0.x; ay += s0 * x0.y; az += s0 * x0.z; aw += s0 * x0.w;
            ax += s1 * x1.x; ay += s1 * x1.y; az += s1 * x1.z; aw += s1 * x1.w;
            ax += s2 * x2.x; ay += s2 * x2.y; az += s2 * x2.z; aw += s2 * x2.w;
            ax += s3 * x3.x; ay += s3 * x3.y; az += s3 * x3.z; aw += s3 * x3.w;
            ax += s4 * x4.x; ay += s4 * x4.y; az += s4 * x4.z; aw += s4 * x4.w;
            ax += s5 * x5.x; ay += s5 * x5.y; az += s5 * x5.z; aw += s5 * x5.w;
            ax += s6 * x6.x; ay += s6 * x6.y; az += s6 * x6.z; aw += s6 * x6.w;
            ax += s7 * x7.x; ay += s7 * x7.y; az += s7 * x7.z; aw += s7 * x7.w;
        } else {
            if (s0 != 0.f) { float4 v = X4[(size_t)u0 * 64 + f4];
                ax += s0 * v.x; ay += s0 * v.y; az += s0 * v.z; aw += s0 * v.w; }
            if (s1 != 0.f) { float4 v = X4[(size_t)u1 * 64 + f4];
                ax += s1 * v.x; ay += s1 * v.y; az += s1 * v.z; aw += s1 * v.w; }
            if (s2 != 0.f) { float4 v = X4[(size_t)u2 * 64 + f4];
                ax += s2 * v.x; ay += s2 * v.y; az += s2 * v.z; aw += s2 * v.w; }
            if (s3 != 0.f) { float4 v = X4[(size_t)u3 * 64 + f4];
                ax += s3 * v.x; ay += s3 * v.y; az += s3 * v.z; aw += s3 * v.w; }
            if (s4 != 0.f) { float4 v = X4[(size_t)u4 * 64 + f4];
                ax += s4 * v.x; ay += s4 * v.y; az += s4 * v.z; aw += s4 * v.w; }
            if (s5 != 0.f) { float4 v = X4[(size_t)u5 * 64 + f4];
                ax += s5 * v.x; ay += s5 * v.y; az += s5 * v.z; aw += s5 * v.w; }
            if (s6 != 0.f) { float4 v = X4[(size_t)u6 * 64 + f4];
                ax += s6 * v.x; ay += s6 * v.y; az += s6 * v.z; aw += s6 * v.w; }
            if (s7 != 0.f) { float4 v = X4[(size_t)u7 * 64 + f4];
                ax += s7 * v.x; ay += s7 * v.y; az += s7 * v.z; aw += s7 * v.w; }
        }
    }
    for (; e + 3 < e1; e += 4) {
        int u0 = col[e], u1 = col[e + 1], u2 = col[e + 2], u3 = col[e + 3];
        float s0 = s[u0], s1 = s[u1], s2 = s[u2], s3 = s[u3];
        if (!MASKED) {
            float4 x0 = X4[(size_t)u0 * 64 + f4];
            float4 x1 = X4[(size_t)u1 * 64 + f4];
            float4 x2 = X4[(size_t)u2 * 64 + f4];
            float4 x3 = X4[(size_t)u3 * 64 + f4];
            ax += s0 * x0.x; ay += s0 * x0.y; az += s0 * x0.z; aw += s0 * x0.w;
            ax += s1 * x1.x; ay += s1 * x1.y; az += s1 * x1.z; aw += s1 * x1.w;
            ax += s2 * x2.x; ay += s2 * x2.y; az += s2 * x2.z; aw += s2 * x2.w;
            ax += s3 * x3.x; ay += s3 * x3.y; az += s3 * x3.z; aw += s3 * x3.w;
        } else {
            if (s0 != 0.f) { float4 v = X4[(size_t)u0 * 64 + f4];
                ax += s0 * v.x; ay += s0 * v.y; az += s0 * v.z; aw += s0 * v.w; }
            if (s1 != 0.f) { float4 v = X4[(size_t)u1 * 64 + f4];
                ax += s1 * v.x; ay += s1 * v.y; az += s1 * v.z; aw += s1 * v.w; }
            if (s2 != 0.f) { float4 v = X4[(size_t)u2 * 64 + f4];
                ax += s2 * v.x; ay += s2 * v.y; az += s2 * v.z; aw += s2 * v.w; }
            if (s3 != 0.f) { float4 v = X4[(size_t)u3 * 64 + f4];
                ax += s3 * v.x; ay += s3 * v.y; az += s3 * v.z; aw += s3 * v.w; }
        }
    }
    for (; e < e1; ++e) {
        int u = col[e];
        float sc = s[u];
        if (!MASKED || sc != 0.f) {
            float4 xv = X4[(size_t)u * 64 + f4];
            ax += sc * xv.x; ay += sc * xv.y; az += sc * xv.z; aw += sc * xv.w;
        }
    }
    if (SPLIT) {
        ushort4 hv, lv;
        split4(ax * tv, ay * tv, az * tv, aw * tv, hv, lv);
        *(ushort4*)&oh[(size_t)node * 256 + f4 * 4] = hv;
        *(ushort4*)&ol[(size_t)node * 256 + f4 * 4] = lv;
    } else {
        float4 r; r.x = ax * tv; r.y = ay * tv; r.z = az * tv; r.w = aw * tv;
        ((float4*)out)[(size_t)node * 64 + f4] = r;
    }
}

// ---------------- post-GEMM 128-dim gather for dec1 (R11 reorder) ----------------
__global__ void agg_bias_128_kernel(const int* __restrict__ row_ptr, const int* __restrict__ col,
                                    const float* __restrict__ P, const float* __restrict__ t,
                                    const float* __restrict__ bias, float* __restrict__ out, int n) {
    int tid = threadIdx.x;
    int node = blockIdx.x * 8 + (tid >> 5);
    int f4 = tid & 31;
    if (node >= n) return;
    int e0 = row_ptr[node], e1 = row_ptr[node + 1];
    const float4* P4 = (const float4*)P;
    float ax = 0.f, ay = 0.f, az = 0.f, aw = 0.f;
    int e = e0;
    for (; e + 3 < e1; e += 4) {
        int u0 = col[e], u1 = col[e + 1], u2 = col[e + 2], u3 = col[e + 3];
        float4 x0 = P4[(size_t)u0 * 32 + f4];
        float4 x1 = P4[(size_t)u1 * 32 + f4];
        float4 x2 = P4[(size_t)u2 * 32 + f4];
        float4 x3 = P4[(size_t)u3 * 32 + f4];
        ax += x0.x; ay += x0.y; az += x0.z; aw += x0.w;
        ax += x1.x; ay += x1.y; az += x1.z; aw += x1.w;
        ax += x2.x; ay += x2.y; az += x2.z; aw += x2.w;
        ax += x3.x; ay += x3.y; az += x3.z; aw += x3.w;
    }
    for (; e < e1; ++e) {
        int u = col[e];
        float4 q = P4[(size_t)u * 32 + f4];
        ax += q.x; ay += q.y; az += q.z; aw += q.w;
    }
    float tv = t[node];
    float4 bv = ((const float4*)bias)[f4];
    float4 r;
    r.x = ax * tv + bv.x; r.y = ay * tv + bv.y;
    r.z = az * tv + bv.z; r.w = aw * tv + bv.w;
    ((float4*)out)[(size_t)node * 32 + f4] = r;
}

// ================= split-bf16 MFMA GEMM =================
// f32 GEMM emulated as Ah@Wh + Ah@Wl + Al@Wh; both operands pre-split by the
// producer kernels. 128x128 tile, 2x2 wave grid, each wave 64x64 (mf4 nf4).

// one-shot: split+transpose all 6 weight matrices into [N][K] hi/lo planes
// segments: embed(128x256) enc0,enc1,bot,dec0(256x256) dec1(256x128); total 327680 elems
__global__ void wsplit_all_kernel(const float* __restrict__ W0, const float* __restrict__ W1,
                                  const float* __restrict__ W2, const float* __restrict__ W3,
                                  const float* __restrict__ W4, const float* __restrict__ W5,
                                  unsigned short* __restrict__ H, unsigned short* __restrict__ L) {
    int i = blockIdx.x * blockDim.x + threadIdx.x;
    const float* W; int rel, base, outIdx;
    if (i < 32768) { W = W0; rel = i; base = 0;
        int k = rel >> 8, nn = rel & 255; outIdx = nn * 128 + k; }
    else if (i < 98304) { W = W1; rel = i - 32768; base = 32768;
        int k = rel >> 8, nn = rel & 255; outIdx = nn * 256 + k; }
    else if (i < 163840) { W = W2; rel = i - 98304; base = 98304;
        int k = rel >> 8, nn = rel & 255; outIdx = nn * 256 + k; }
    else if (i < 229376) { W = W3; rel = i - 163840; base = 163840;
        int k = rel >> 8, nn = rel & 255; outIdx = nn * 256 + k; }
    else if (i < 294912) { W = W4; rel = i - 229376; base = 229376;
        int k = rel >> 8, nn = rel & 255; outIdx = nn * 256 + k; }
    else { W = W5; rel = i - 294912; base = 294912;
        int k = rel >> 7, nn = rel & 127; outIdx = nn * 256 + k; }
    float x = W[rel];
    unsigned short h = f2bf(x);
    H[base + outIdx] = h;
    L[base + outIdx] = f2bf(x - bf2f(h));
}

// full-rows 128x128 MFMA GEMM
template <bool RELU>
__global__ __launch_bounds__(256, 3) void gemm_mfma_kernel(
    const unsigned short* __restrict__ Ah, const unsigned short* __restrict__ Al,
    const unsigned short* __restrict__ Wh, const unsigned short* __restrict__ Wl,
    const float* __restrict__ bias, float* __restrict__ C, int M, int K, int Nn) {
    __shared__ __align__(16) short sAh[128][40];
    __shared__ __align__(16) short sAl[128][40];
    __shared__ __align__(16) short sWh[128][40];
    __shared__ __align__(16) short sWl[128][40];
    int tid = threadIdx.x;
    int bm = blockIdx.x * 128, bn = blockIdx.y * 128;
    int lane = tid & 63, wid = tid >> 6;
    int wr = (wid >> 1) * 64, wc = (wid & 1) * 64;
    int lr = lane & 15, kg = lane >> 4;
    int arow = tid >> 1, akq = (tid & 1) * 16;   // 16 shorts/thread/plane, 2 thr/row
    const unsigned short* ahp = Ah + (size_t)(bm + arow) * K + akq;
    const unsigned short* alp = Al + (size_t)(bm + arow) * K + akq;
    const unsigned short* whp = Wh + (size_t)(bn + arow) * K + akq;
    const unsigned short* wlp = Wl + (size_t)(bn + arow) * K + akq;
    f32x4 acc[4][4];
    #pragma unroll
    for (int i = 0; i < 4; ++i)
        #pragma unroll
        for (int j = 0; j < 4; ++j) acc[i][j] = (f32x4){0.f, 0.f, 0.f, 0.f};
    for (int k0 = 0; k0 < K; k0 += 32) {
        short8v a0 = *(const short8v*)(ahp + k0);
        short8v a1 = *(const short8v*)(ahp + k0 + 8);
        short8v l0 = *(const short8v*)(alp + k0);
        short8v l1 = *(const short8v*)(alp + k0 + 8);
        short8v w0 = *(const short8v*)(whp + k0);
        short8v w1 = *(const short8v*)(whp + k0 + 8);
        short8v v0 = *(const short8v*)(wlp + k0);
        short8v v1 = *(const short8v*)(wlp + k0 + 8);
        __syncthreads();   // previous iter's fragment reads done before overwrite
        *(short8v*)&sAh[arow][akq] = a0; *(short8v*)&sAh[arow][akq + 8] = a1;
        *(short8v*)&sAl[arow][akq] = l0; *(short8v*)&sAl[arow][akq + 8] = l1;
        *(short8v*)&sWh[arow][akq] = w0; *(short8v*)&sWh[arow][akq + 8] = w1;
        *(short8v*)&sWl[arow][akq] = v0; *(short8v*)&sWl[arow][akq + 8] = v1;
        __syncthreads();
        short8v ah[4], al[4];
        #pragma unroll
        for (int mf = 0; mf < 4; ++mf) {
            ah[mf] = *(const short8v*)&sAh[wr + mf * 16 + lr][kg * 8];
            al[mf] = *(const short8v*)&sAl[wr + mf * 16 + lr][kg * 8];
        }
        #pragma unroll
        for (int nf = 0; nf < 4; ++nf) {
            short8v bh = *(const short8v*)&sWh[wc + nf * 16 + lr][kg * 8];
            short8v bl = *(const short8v*)&sWl[wc + nf * 16 + lr][kg * 8];
            #pragma unroll
            for (int mf = 0; mf < 4; ++mf) {
                acc[mf][nf] = __builtin_amdgcn_mfma_f32_16x16x32_bf16(ah[mf], bh, acc[mf][nf], 0, 0, 0);
                acc[mf][nf] = __builtin_amdgcn_mfma_f32_16x16x32_bf16(ah[mf], bl, acc[mf][nf], 0, 0, 0);
                acc[mf][nf] = __builtin_amdgcn_mfma_f32_16x16x32_bf16(al[mf], bh, acc[mf][nf], 0, 0, 0);
            }
        }
    }
    // epilogue: D mapping col=lane&15, row=(lane>>4)*4+reg (m89-verified)
    #pragma unroll
    for (int mf = 0; mf < 4; ++mf) {
        #pragma unroll
        for (int nf = 0; nf < 4; ++nf) {
            int col = bn + wc + nf * 16 + lr;
            float bv = bias ? bias[col] : 0.f;
            #pragma unroll
            for (int r = 0; r < 4; ++r) {
                int grow = bm + wr + mf * 16 + kg * 4 + r;
                if (grow < M) {
                    float x = acc[mf][nf][r] + bv;
                    if (RELU) x = fmaxf(x, 0.f);
                    C[(size_t)grow * Nn + col] = x;
                }
            }
        }
    }
}

// compacted-row-list variant (enc1 / bot / dec0)
template <bool RELU>
__global__ __launch_bounds__(256, 3) void gemm_rows_mfma_kernel(
    const unsigned short* __restrict__ Ah, const unsigned short* __restrict__ Al,
    const unsigned short* __restrict__ Wh, const unsigned short* __restrict__ Wl,
    const float* __restrict__ bias, const int* __restrict__ idx, int Mc,
    float* __restrict__ C, int K, int Nn) {
    __shared__ __align__(16) short sAh[128][40];
    __shared__ __align__(16) short sAl[128][40];
    __shared__ __align__(16) short sWh[128][40];
    __shared__ __align__(16) short sWl[128][40];
    __shared__ int ridx[128];
    int tid = threadIdx.x;
    int bm = blockIdx.x * 128, bn = blockIdx.y * 128;
    int lane = tid & 63, wid = tid >> 6;
    int wr = (wid >> 1) * 64, wc = (wid & 1) * 64;
    int lr = lane & 15, kg = lane >> 4;
    int arow = tid >> 1, akq = (tid & 1) * 16;
    if (tid < 128) {
        int r = bm + tid;
        ridx[tid] = (r < Mc) ? idx[r] : idx[0];
    }
    __syncthreads();
    int rA = ridx[arow];
    const unsigned short* ahp = Ah + (size_t)rA * K + akq;
    const unsigned short* alp = Al + (size_t)rA * K + akq;
    const unsigned short* whp = Wh + (size_t)(bn + arow) * K + akq;
    const unsigned short* wlp = Wl + (size_t)(bn + arow) * K + akq;
    f32x4 acc[4][4];
    #pragma unroll
    for (int i = 0; i < 4; ++i)
        #pragma unroll
        for (int j = 0; j < 4; ++j) acc[i][j] = (f32x4){0.f, 0.f, 0.f, 0.f};
    for (int k0 = 0; k0 < K; k0 += 32) {
        short8v a0 = *(const short8v*)(ahp + k0);
        short8v a1 = *(const short8v*)(ahp + k0 + 8);
        short8v l0 = *(const short8v*)(alp + k0);
        short8v l1 = *(const short8v*)(alp + k0 + 8);
        short8v w0 = *(const short8v*)(whp + k0);
        short8v w1 = *(const short8v*)(whp + k0 + 8);
        short8v v0 = *(const short8v*)(wlp + k0);
        short8v v1 = *(const short8v*)(wlp + k0 + 8);
        __syncthreads();
        *(short8v*)&sAh[arow][akq] = a0; *(short8v*)&sAh[arow][akq + 8] = a1;
        *(short8v*)&sAl[arow][akq] = l0; *(short8v*)&sAl[arow][akq + 8] = l1;
        *(short8v*)&sWh[arow][akq] = w0; *(short8v*)&sWh[arow][akq + 8] = w1;
        *(short8v*)&sWl[arow][akq] = v0; *(short8v*)&sWl[arow][akq + 8] = v1;
        __syncthreads();
        short8v ah[4], al[4];
        #pragma unroll
        for (int mf = 0; mf < 4; ++mf) {
            ah[mf] = *(const short8v*)&sAh[wr + mf * 16 + lr][kg * 8];
            al[mf] = *(const short8v*)&sAl[wr + mf * 16 + lr][kg * 8];
        }
        #pragma unroll
        for (int nf = 0; nf < 4; ++nf) {
            short8v bh = *(const short8v*)&sWh[wc + nf * 16 + lr][kg * 8];
            short8v bl = *(const short8v*)&sWl[wc + nf * 16 + lr][kg * 8];
            #pragma unroll
            for (int mf = 0; mf < 4; ++mf) {
                acc[mf][nf] = __builtin_amdgcn_mfma_f32_16x16x32_bf16(ah[mf], bh, acc[mf][nf], 0, 0, 0);
                acc[mf][nf] = __builtin_amdgcn_mfma_f32_16x16x32_bf16(ah[mf], bl, acc[mf][nf], 0, 0, 0);
                acc[mf][nf] = __builtin_amdgcn_mfma_f32_16x16x32_bf16(al[mf], bh, acc[mf][nf], 0, 0, 0);
            }
        }
    }
    #pragma unroll
    for (int mf = 0; mf < 4; ++mf) {
        #pragma unroll
        for (int nf = 0; nf < 4; ++nf) {
            int col = bn + wc + nf * 16 + lr;
            float bv = bias[col];
            #pragma unroll
            for (int r = 0; r < 4; ++r) {
                int lrow = wr + mf * 16 + kg * 4 + r;
                if (bm + lrow < Mc) {
                    int grow = ridx[lrow];
                    float x = acc[mf][nf][r] + bv;
                    if (RELU) x = fmaxf(x, 0.f);
                    C[(size_t)grow * Nn + col] = x;
                }
            }
        }
    }
}

// dec1 GEMM with fused input: A-staging computes ((mask?A:0)+B)*rs and splits
// in-registers (replaces the add_split kernel's 100 MB round trip). Nn=128.
__global__ __launch_bounds__(256, 3) void gemm_dec1_kernel(
    const float* __restrict__ A, const float* __restrict__ B,
    const float* __restrict__ mask, const float* __restrict__ rs,
    const unsigned short* __restrict__ Wh, const unsigned short* __restrict__ Wl,
    float* __restrict__ C, int M, int K) {
    __shared__ __align__(16) short sAh[128][40];
    __shared__ __align__(16) short sAl[128][40];
    __shared__ __align__(16) short sWh[128][40];
    __shared__ __align__(16) short sWl[128][40];
    const int Nn = 128;
    int tid = threadIdx.x;
    int bm = blockIdx.x * 128, bn = 0;
    int lane = tid & 63, wid = tid >> 6;
    int wr = (wid >> 1) * 64, wc = (wid & 1) * 64;
    int lr = lane & 15, kg = lane >> 4;
    int arow = tid >> 1, akq = (tid & 1) * 16;
    float mv = (mask[bm + arow] != 0.f) ? 1.f : 0.f;
    float rsv = rs[bm + arow];
    const float* apf = A + (size_t)(bm + arow) * K + akq;
    const float* bpf = B + (size_t)(bm + arow) * K + akq;
    const unsigned short* whp = Wh + (size_t)(bn + arow) * K + akq;
    const unsigned short* wlp = Wl + (size_t)(bn + arow) * K + akq;
    f32x4 acc[4][4];
    #pragma unroll
    for (int i = 0; i < 4; ++i)
        #pragma unroll
        for (int j = 0; j < 4; ++j) acc[i][j] = (f32x4){0.f, 0.f, 0.f, 0.f};
    for (int k0 = 0; k0 < K; k0 += 32) {
        const float4* pa = (const float4*)(apf + k0);
        const float4* pb = (const float4*)(bpf + k0);
        float4 qa0 = pa[0], qa1 = pa[1], qa2 = pa[2], qa3 = pa[3];
        float4 qb0 = pb[0], qb1 = pb[1], qb2 = pb[2], qb3 = pb[3];
        ushort4 h0, l0v, h1, l1v, h2, l2v, h3, l3v;
        split4((qa0.x * mv + qb0.x) * rsv, (qa0.y * mv + qb0.y) * rsv,
               (qa0.z * mv + qb0.z) * rsv, (qa0.w * mv + qb0.w) * rsv, h0, l0v);
        split4((qa1.x * mv + qb1.x) * rsv, (qa1.y * mv + qb1.y) * rsv,
               (qa1.z * mv + qb1.z) * rsv, (qa1.w * mv + qb1.w) * rsv, h1, l1v);
        split4((qa2.x * mv + qb2.x) * rsv, (qa2.y * mv + qb2.y) * rsv,
               (qa2.z * mv + qb2.z) * rsv, (qa2.w * mv + qb2.w) * rsv, h2, l2v);
        split4((qa3.x * mv + qb3.x) * rsv, (qa3.y * mv + qb3.y) * rsv,
               (qa3.z * mv + qb3.z) * rsv, (qa3.w * mv + qb3.w) * rsv, h3, l3v);
        short8v w0 = *(const short8v*)(whp + k0);
        short8v w1 = *(const short8v*)(whp + k0 + 8);
        short8v v0 = *(const short8v*)(wlp + k0);
        short8v v1 = *(const short8v*)(wlp + k0 + 8);
        __syncthreads();
        *(ushort4*)&sAh[arow][akq]      = h0; *(ushort4*)&sAh[arow][akq + 4]  = h1;
        *(ushort4*)&sAh[arow][akq + 8]  = h2; *(ushort4*)&sAh[arow][akq + 12] = h3;
        *(ushort4*)&sAl[arow][akq]      = l0v; *(ushort4*)&sAl[arow][akq + 4]  = l1v;
        *(ushort4*)&sAl[arow][akq + 8]  = l2v; *(ushort4*)&sAl[arow][akq + 12] = l3v;
        *(short8v*)&sWh[arow][akq] = w0; *(short8v*)&sWh[arow][akq + 8] = w1;
        *(short8v*)&sWl[arow][akq] = v0; *(short8v*)&sWl[arow][akq + 8] = v1;
        __syncthreads();
        short8v ah[4], al[4];
        #pragma unroll
        for (int mf = 0; mf < 4; ++mf) {
            ah[mf] = *(const short8v*)&sAh[wr + mf * 16 + lr][kg * 8];
            al[mf] = *(const short8v*)&sAl[wr + mf * 16 + lr][kg * 8];
        }
        #pragma unroll
        for (int nf = 0; nf < 4; ++nf) {
            short8v bh = *(const short8v*)&sWh[wc + nf * 16 + lr][kg * 8];
            short8v bl = *(const short8v*)&sWl[wc + nf * 16 + lr][kg * 8];
            #pragma unroll
            for (int mf = 0; mf < 4; ++mf) {
                acc[mf][nf] = __builtin_amdgcn_mfma_f32_16x16x32_bf16(ah[mf], bh, acc[mf][nf], 0, 0, 0);
                acc[mf][nf] = __builtin_amdgcn_mfma_f32_16x16x32_bf16(ah[mf], bl, acc[mf][nf], 0, 0, 0);
                acc[mf][nf] = __builtin_amdgcn_mfma_f32_16x16x32_bf16(al[mf], bh, acc[mf][nf], 0, 0, 0);
            }
        }
    }
    #pragma unroll
    for (int mf = 0; mf < 4; ++mf) {
        #pragma unroll
        for (int nf = 0; nf < 4; ++nf) {
            int col = bn + wc + nf * 16 + lr;
            #pragma unroll
            for (int r = 0; r < 4; ++r) {
                int grow = bm + wr + mf * 16 + kg * 4 + r;
                if (grow < M) C[(size_t)grow * Nn + col] = acc[mf][nf][r];
            }
        }
    }
}

// ---------------- legacy vector GEMM (non-fast fallback only) ----------------
template <bool RELU>
__global__ __launch_bounds__(256) void gemm_kernel(const float* __restrict__ A,
                                                   const float* __restrict__ W,
                                                   const float* __restrict__ bias,
                                                   const float* __restrict__ mask,
                                                   const float* __restrict__ rowscale,
                                                   float* __restrict__ C, int M, int K, int Nn) {
    __shared__ float As[16][68];
    __shared__ float Bs[16][132];
    int tid = threadIdx.x;
    int bm = blockIdx.x * 64, bn = blockIdx.y * 128;
    int mA = tid >> 2, kqA = (tid & 3) * 4;
    int kB = tid >> 4, nqB = (tid & 15) * 8;
    int tm = (tid >> 4) * 4, tn = (tid & 15) * 4;
    float acc[4][8] = {};
    float rs = rowscale ? rowscale[bm + mA] : 1.f;
    for (int k0 = 0; k0 < K; k0 += 16) {
        float4 av = *(const float4*)(A + (size_t)(bm + mA) * K + k0 + kqA);
        As[kqA + 0][mA] = av.x * rs; As[kqA + 1][mA] = av.y * rs;
        As[kqA + 2][mA] = av.z * rs; As[kqA + 3][mA] = av.w * rs;
        const float* wp = W + (size_t)(k0 + kB) * Nn + bn + nqB;
        *(float4*)&Bs[kB][nqB]     = *(const float4*)wp;
        *(float4*)&Bs[kB][nqB + 4] = *(const float4*)(wp + 4);
        __syncthreads();
        #pragma unroll
        for (int kk = 0; kk < 16; ++kk) {
            float4 a  = *(const float4*)&As[kk][tm];
            float4 b0 = *(const float4*)&Bs[kk][tn];
            float4 b1 = *(const float4*)&Bs[kk][tn + 64];
            float ar[4] = {a.x, a.y, a.z, a.w};
            float br[8] = {b0.x, b0.y, b0.z, b0.w, b1.x, b1.y, b1.z, b1.w};
            #pragma unroll
            for (int i2 = 0; i2 < 4; i2++)
                #pragma unroll
                for (int j = 0; j < 8; j++) acc[i2][j] += ar[i2] * br[j];
        }
        __syncthreads();
    }
    #pragma unroll
    for (int i2 = 0; i2 < 4; i2++) {
        int row = bm + tm + i2;
        if (row < M) {
            float mv = mask ? mask[row] : 1.f;
            float o[8];
            #pragma unroll
            for (int j = 0; j < 8; j++) {
                int cj = (j < 4) ? (tn + j) : (64 + tn + j - 4);
                float x = acc[i2][j] + (bias ? bias[bn + cj] : 0.f);
                if (RELU) x = fmaxf(x, 0.f);
                o[j] = x * mv;
            }
            float* cp = C + (size_t)row * Nn + bn;
            *(float4*)(cp + tn)      = make_float4(o[0], o[1], o[2], o[3]);
            *(float4*)(cp + 64 + tn) = make_float4(o[4], o[5], o[6], o[7]);
        }
    }
}

// ---------------- pooling score ----------------
__global__ void score_kernel(const float* __restrict__ H, const float* __restrict__ Wp,
                             const float* __restrict__ bp, const float* __restrict__ mask,
                             float* __restrict__ scores, float* __restrict__ keys, int n) {
    int lane = threadIdx.x & 63;
    int node = blockIdx.x * 4 + (threadIdx.x >> 6);
    if (node >= n) return;
    float4 hv = ((const float4*)(H + (size_t)node * 256))[lane];
    float4 wq = ((const float4*)Wp)[lane];
    float d = hv.x * wq.x + hv.y * wq.y + hv.z * wq.z + hv.w * wq.w;
    #pragma unroll
    for (int off = 32; off > 0; off >>= 1) d += __shfl_down(d, off);
    if (lane == 0) {
        float sc = 1.f / (1.f + expf(-(d + bp[0])));
        scores[node] = sc;
        keys[node] = (mask && mask[node] == 0.f) ? -1e9f : sc;
    }
}

// ---------------- top-K selection ----------------
__device__ __forceinline__ unsigned key_u(float f) {
    unsigned u = __float_as_uint(f);
    return (u & 0x80000000u) ? ~u : (u | 0x80000000u);
}

__device__ __forceinline__ void wave_hist_add(int* __restrict__ hist, unsigned bin, bool valid) {
    int lane = threadIdx.x & 63;
    while (true) {
        unsigned long long vmask = __ballot(valid);
        if (vmask == 0ull) break;
        int leader = __ffsll((long long)vmask) - 1;
        unsigned lbin = (unsigned)__shfl((int)bin, leader);
        bool match = valid && (bin == lbin);
        unsigned long long mmask = __ballot(match);
        if (lane == leader) atomicAdd(&hist[lbin], __popcll(mmask));
        if (match) valid = false;
    }
}

// -------- fallback: single block radix select --------
__global__ void topk_kernel(const float* __restrict__ keys, const float* __restrict__ scores,
                            float* __restrict__ nm, float* __restrict__ gate, int n, int K) {
    __shared__ int hist[256];
    __shared__ unsigned sh_prefix;
    __shared__ int sh_krem;
    __shared__ int sh_running;
    __shared__ int wsum[16];
    int tid = threadIdx.x, lane = tid & 63, wid = tid >> 6;
    if (tid == 0) { sh_prefix = 0u; sh_krem = K; sh_running = 0; }
    __syncthreads();
    for (int pass = 0; pass < 4; ++pass) {
        int shift = 24 - pass * 8;
        if (tid < 256) hist[tid] = 0;
        __syncthreads();
        unsigned pmask = (pass == 0) ? 0u : (0xFFFFFFFFu << (shift + 8));
        unsigned prefix = sh_prefix;
        for (int i = tid; i < n; i += 1024) {
            unsigned u = key_u(keys[i]);
            if ((u & pmask) == prefix) atomicAdd(&hist[(u >> shift) & 0xFF], 1);
        }
        __syncthreads();
        if (tid == 0) {
            int krem = sh_krem;
            int b;
            for (b = 255; b > 0; --b) {
                int c = hist[b];
                if (c >= krem) break;
                krem -= c;
            }
            sh_prefix = prefix | ((unsigned)b << shift);
            sh_krem = krem;
        }
        __syncthreads();
    }
    unsigned Tkey = sh_prefix;
    int need_eq = sh_krem;
    for (int base = 0; base < n; base += 1024) {
        int i = base + tid;
        unsigned u = 0; int flagv = 0;
        if (i < n) { u = key_u(keys[i]); flagv = (u == Tkey) ? 1 : 0; }
        unsigned long long bal = __ballot(flagv);
        int rank_w = __popcll(bal & ((1ull << lane) - 1ull));
        if (lane == 63) wsum[wid] = __popcll(bal);
        __syncthreads();
        int woff = 0;
        for (int w = 0; w < wid; ++w) woff += wsum[w];
        int grank = sh_running + woff + rank_w;
        if (i < n) {
            float v = (u > Tkey) ? 1.f : ((flagv && grank < need_eq) ? 1.f : 0.f);
            nm[i] = v;
            gate[i] = v * scores[i];
        }
        __syncthreads();
        if (tid == 0) {
            int tot = 0;
            for (int w = 0; w < 16; ++w) tot += wsum[w];
            sh_running += tot;
        }
        __syncthreads();
    }
}

// -------- fast path: grid-wide radix select, 2 passes of 16 bits --------
__global__ void topk_hist1(const float* __restrict__ keys, int n, int* __restrict__ hist) {
    int i = blockIdx.x * blockDim.x + threadIdx.x;
    unsigned bin = 0; bool valid = (i < n);
    if (valid) bin = key_u(keys[i]) >> 16;
    wave_hist_add(hist, bin, valid);
}

__global__ void topk_scan1(const int* __restrict__ hist, int K, int* __restrict__ sel) {
    __shared__ int arr[1024];
    int tid = threadIdx.x;
    int base = tid * 64;
    int local = 0;
    #pragma unroll 8
    for (int b = 0; b < 64; ++b) local += hist[base + b];
    arr[tid] = local;
    __syncthreads();
    for (int off = 1; off < 1024; off <<= 1) {
        int v = (tid + off < 1024) ? arr[tid + off] : 0;
        __syncthreads();
        arr[tid] += v;
        __syncthreads();
    }
    int above = arr[tid] - local;
    if (above < K && arr[tid] >= K) {
        int run = above;
        for (int b = base + 63; b >= base; --b) {
            int c = hist[b];
            if (run + c >= K) { sel[0] = b; sel[1] = K - run; break; }
            run += c;
        }
    }
}

__global__ void topk_hist2(const float* __restrict__ keys, int n, const int* __restrict__ sel,
                           int* __restrict__ hist) {
    int i = blockIdx.x * blockDim.x + threadIdx.x;
    unsigned bin = 0; bool valid = false;
    if (i < n) {
        unsigned u = key_u(keys[i]);
        if ((int)(u >> 16) == sel[0]) { bin = u & 0xFFFF; valid = true; }
    }
    wave_hist_add(hist, bin, valid);
}

__global__ void topk_scan2(const int* __restrict__ hist, int* __restrict__ sel,
                           int* __restrict__ tie_cnt) {
    __shared__ int arr[1024];
    int tid = threadIdx.x;
    if (tid == 0) *tie_cnt = 0;
    int K = sel[1];
    int base = tid * 64;
    int local = 0;
    #pragma unroll 8
    for (int b = 0; b < 64; ++b) local += hist[base + b];
    arr[tid] = local;
    __syncthreads();
    for (int off = 1; off < 1024; off <<= 1) {
        int v = (tid + off < 1024) ? arr[tid + off] : 0;
        __syncthreads();
        arr[tid] += v;
        __syncthreads();
    }
    int above = arr[tid] - local;
    if (above < K && arr[tid] >= K) {
        int run = above;
        for (int b = base + 63; b >= base; --b) {
            int c = hist[b];
            if (run + c >= K) {
                sel[2] = (int)((((unsigned)sel[0]) << 16) | (unsigned)b);
                sel[3] = K - run;
                break;
            }
            run += c;
        }
    }
}

__global__ void topk_mark(const float* __restrict__ keys, const float* __restrict__ scores,
                          const int* __restrict__ sel, float* __restrict__ nm,
                          float* __restrict__ gate, int* __restrict__ tie_list,
                          int* __restrict__ tie_cnt, int n) {
    int i = blockIdx.x * blockDim.x + threadIdx.x;
    if (i >= n) return;
    unsigned Tkey = (unsigned)sel[2];
    unsigned u = key_u(keys[i]);
    float v = 0.f;
    if (u > Tkey) v = 1.f;
    else if (u == Tkey) { int p = atomicAdd(tie_cnt, 1); tie_list[p] = i; }
    nm[i] = v;
    gate[i] = v * scores[i];
}

__global__ void topk_ties(const float* __restrict__ scores, const int* __restrict__ sel,
                          const int* __restrict__ tie_list, const int* __restrict__ tie_cnt,
                          float* __restrict__ nm, float* __restrict__ gate) {
    int cnt = *tie_cnt;
    int need = sel[3];
    for (int j = threadIdx.x; j < cnt; j += blockDim.x) {
        int idx = tie_list[j];
        int rank = 0;
        for (int k2 = 0; k2 < cnt; ++k2) rank += (tie_list[k2] < idx) ? 1 : 0;
        if (rank < need) { nm[idx] = 1.f; gate[idx] = scores[idx]; }
    }
}

// ---------------- selected-row compaction (order-independent) ----------------
__global__ void compact_kernel(const float* __restrict__ nm, int* __restrict__ idx,
                               int* __restrict__ cnt, int n) {
    int i = blockIdx.x * blockDim.x + threadIdx.x;
    if (i < n && nm[i] != 0.f) {
        int p = atomicAdd(cnt, 1);
        idx[p] = i;
    }
}

// ---------------- adds ----------------
__global__ void add_mask_kernel(float* __restrict__ A, const float* __restrict__ B,
                                const float* __restrict__ mask, int n4) {
    int i = blockIdx.x * blockDim.x + threadIdx.x;
    if (i < n4) {
        float4 a = ((float4*)A)[i];
        float4 b = ((const float4*)B)[i];
        if (mask && mask[i >> 6] == 0.f) { a.x = 0.f; a.y = 0.f; a.z = 0.f; a.w = 0.f; }
        a.x += b.x; a.y += b.y; a.z += b.z; a.w += b.w;
        ((float4*)A)[i] = a;
    }
}

extern "C" void kernel_launch(void* const* d_in, const int* in_sizes, int n_in,
                              void* d_out, int out_size, void* d_ws, size_t ws_size,
                              hipStream_t stream) {
    const int n = in_sizes[0] / 128;   // 50000
    const int E = in_sizes[1];         // 800000
    const int NPAD = ((n + 127) / 128) * 128;   // 128-divisible for MFMA tiles
    const int K1 = 25000, K2 = 12500;

    const float* features = (const float*)d_in[0];
    const int* src = (const int*)d_in[1];
    const int* dst = (const int*)d_in[2];
    const float* W_embed = (const float*)d_in[3];
    const float* b_embed = (const float*)d_in[4];
    const float* W_enc0  = (const float*)d_in[5];
    const float* b_enc0  = (const float*)d_in[6];
    const float* W_enc1  = (const float*)d_in[7];
    const float* b_enc1  = (const float*)d_in[8];
    const float* W_p0    = (const float*)d_in[9];
    const float* b_p0    = (const float*)d_in[10];
    const float* W_p1    = (const float*)d_in[11];
    const float* b_p1    = (const float*)d_in[12];
    const float* W_bot   = (const float*)d_in[13];
    const float* b_bot   = (const float*)d_in[14];
    const float* W_dec0  = (const float*)d_in[15];
    const float* b_dec0  = (const float*)d_in[16];
    const float* W_dec1  = (const float*)d_in[17];
    const float* b_dec1  = (const float*)d_in[18];
    float* out_f = (float*)d_out;

    char* ws = (char*)d_ws;
    size_t off = 0;
    auto alloc = [&](size_t bytes) -> void* {
        void* p = ws + off;
        off += (bytes + 255) & ~(size_t)255;
        return p;
    };
    (void)alloc(256);  // pad (R2 'flag' slot)
    int* row_ptr  = (int*)alloc((size_t)(n + 1) * 4);
    int* cursor   = (int*)alloc((size_t)n * 4);
    int* col      = (int*)alloc((size_t)E * 4);
    int* deg_out_i= (int*)alloc((size_t)n * 4);
    int* deg_in_i = (int*)alloc((size_t)n * 4);
    float* so_m1  = (float*)alloc((size_t)n * 4);
    float* si_m1  = (float*)alloc((size_t)n * 4);
    float* so_m2  = (float*)alloc((size_t)n * 4);
    float* si_m2  = (float*)alloc((size_t)n * 4);
    float* sarr   = (float*)alloc((size_t)n * 4);
    float* tarr   = (float*)alloc((size_t)n * 4);
    float* scores1= (float*)alloc((size_t)n * 4);
    float* keys1  = (float*)alloc((size_t)n * 4);
    float* scores2= (float*)alloc((size_t)n * 4);
    float* keys2  = (float*)alloc((size_t)n * 4);
    float* nm1    = (float*)alloc((size_t)n * 4);
    float* gate1  = (float*)alloc((size_t)n * 4);
    float* nm2    = (float*)alloc((size_t)n * 4);
    float* gate2  = (float*)alloc((size_t)n * 4);
    size_t big = (size_t)NPAD * 256 * 4;
    float* A = (float*)alloc(big);
    float* B = (float*)alloc(big);
    float* C = (float*)alloc(big);
    float* D = (float*)alloc(big);   // fast path: holds split hi/lo planes
    // split-plane views of D (hi plane then lo plane, each NPAD*256 ushorts)
    unsigned short* Dh = (unsigned short*)D;
    unsigned short* Dl = Dh + (size_t)NPAD * 256;
    unsigned short* Dh128 = Dh;                        // 128-wide planes (embed)
    unsigned short* Dl128 = Dh + (size_t)NPAD * 128;
    // ---- tail ----
    int* rhist    = (int*)alloc(65536 * 4);
    int* sel      = (int*)alloc(256);
    int* tie_cnt  = (int*)alloc(256);
    int* tie_list = (int*)alloc((size_t)n * 4);
    float* s0     = (float*)alloc((size_t)n * 4);
    float* t0     = (float*)alloc((size_t)n * 4);
    int* idx1     = (int*)alloc((size_t)n * 4);
    int* idx2     = (int*)alloc((size_t)n * 4);
    int* ccnt     = (int*)alloc(256);
    // split-bf16 transposed weight planes: 327680 elems total
    const int WO_EMBED = 0, WO_ENC0 = 32768, WO_ENC1 = 98304,
              WO_BOT = 163840, WO_DEC0 = 229376, WO_DEC1 = 294912;
    const int WTOT = 327680;
    unsigned short* wsph = (unsigned short*)alloc((size_t)WTOT * 2);
    unsigned short* wspl = (unsigned short*)alloc((size_t)WTOT * 2);
    bool fast = (off <= ws_size);

    dim3 blk(256);
    int gE = (E + 255) / 256;
    int gN = (n + 255) / 256;
    int gAgg256 = (n + 3) / 4;
    int gAgg128 = (n + 7) / 8;
    int gScore = (n + 3) / 4;
    dim3 gemm_g(NPAD / 128, 2);            // MFMA 128x128 tiles, Nn=256
    dim3 gemm_g128(NPAD / 128, 1);         // Nn=128 (dec1)
    dim3 gemm_gK1((K1 + 127) / 128, 2);
    dim3 gemm_gK2((K2 + 127) / 128, 2);
    dim3 gemm_gv(NPAD / 64, 2);            // legacy vector GEMM grids (fallback)
    dim3 gemm_gv128(NPAD / 64, 1);
    int gAdd = (n * 64 + 255) / 256;

    auto run_topk = [&](const float* keys, const float* scores, float* nm, float* gate, int K) {
        if (fast) {
            hipMemsetAsync(rhist, 0, 65536 * 4, stream);
            topk_hist1<<<gN, blk, 0, stream>>>(keys, n, rhist);
            topk_scan1<<<1, 1024, 0, stream>>>(rhist, K, sel);
            hipMemsetAsync(rhist, 0, 65536 * 4, stream);
            topk_hist2<<<gN, blk, 0, stream>>>(keys, n, sel, rhist);
            topk_scan2<<<1, 1024, 0, stream>>>(rhist, sel, tie_cnt);
            topk_mark<<<gN, blk, 0, stream>>>(keys, scores, sel, nm, gate, tie_list, tie_cnt, n);
            topk_ties<<<1, 256, 0, stream>>>(scores, sel, tie_list, tie_cnt, nm, gate);
        } else {
            topk_kernel<<<1, 1024, 0, stream>>>(keys, scores, nm, gate, n, K);
        }
    };
    float* sF = fast ? s0 : sarr;
    float* tF = fast ? t0 : tarr;

    // ---- weight split/transpose (once per forward; independent of CSR) ----
    if (fast) {
        wsplit_all_kernel<<<WTOT / 256, blk, 0, stream>>>(W_embed, W_enc0, W_enc1, W_bot,
                                                          W_dec0, W_dec1, wsph, wspl);
    }

    // ---- CSR build ----
    {   // deg_out_i and deg_in_i are consecutive allocations: one memset covers both
        size_t degpad = (((size_t)n * 4) + 255) & ~(size_t)255;
        hipMemsetAsync(deg_out_i, 0, degpad + (size_t)n * 4, stream);
    }
    hist_kernel<<<gE, blk, 0, stream>>>(src, dst, deg_out_i, deg_in_i, E);
    scan_kernel<<<1, 1024, 0, stream>>>(deg_in_i, row_ptr, cursor, n);
    fill_kernel<<<gE, blk, 0, stream>>>(src, dst, cursor, col, E);
    sort_rows_kernel<<<gN, blk, 0, stream>>>(row_ptr, col, n);

    // ---- full-graph degree scales (once) ----
    scale_full_kernel<<<gN, blk, 0, stream>>>(deg_out_i, deg_in_i, sF, tF, n);

    // ---- embed GCN (full graph) -> A ----
    if (fast) {
        agg_feat_128_kernel<true><<<gAgg128, blk, 0, stream>>>(row_ptr, col, features, sF, tF,
                                                               nullptr, Dh128, Dl128, n);
        gemm_mfma_kernel<true><<<gemm_g, blk, 0, stream>>>(Dh128, Dl128, wsph + WO_EMBED,
                                                           wspl + WO_EMBED, b_embed, A, n, 128, 256);
    } else {
        agg_feat_128_kernel<false><<<gAgg128, blk, 0, stream>>>(row_ptr, col, features, sF, tF,
                                                                D, nullptr, nullptr, n);
        gemm_kernel<true><<<gemm_gv, blk, 0, stream>>>(D, W_embed, b_embed, nullptr, nullptr, A, n, 128, 256);
    }

    // ---- enc0 (full graph); hidden0 = B ----
    if (fast) {
        agg_f32_256_kernel<false, true><<<gAgg256, blk, 0, stream>>>(row_ptr, col, A, sF, tF,
                                                                     nullptr, Dh, Dl, n);
        gemm_mfma_kernel<true><<<gemm_g, blk, 0, stream>>>(Dh, Dl, wsph + WO_ENC0, wspl + WO_ENC0,
                                                           b_enc0, B, n, 256, 256);
    } else {
        agg_f32_256_kernel<false, false><<<gAgg256, blk, 0, stream>>>(row_ptr, col, A, sF, tF,
                                                                      D, nullptr, nullptr, n);
        gemm_kernel<true><<<gemm_gv, blk, 0, stream>>>(D, W_enc0, b_enc0, nullptr, nullptr, B, n, 256, 256);
    }

    // ---- pool0 ----
    score_kernel<<<gScore, blk, 0, stream>>>(B, W_p0, b_p0, nullptr, scores1, keys1, n);
    run_topk(keys1, scores1, nm1, gate1, K1);
    if (fast) {
        hipMemsetAsync(ccnt, 0, 4, stream);
        compact_kernel<<<gN, blk, 0, stream>>>(nm1, idx1, ccnt, n);
    }

    // ---- enc1 (mask m1, gated input); hidden1 = C ----
    hipMemsetAsync(so_m1, 0, (size_t)n * 4, stream);
    out_deg_mask_kernel<<<gE, blk, 0, stream>>>(src, dst, nm1, so_m1, E);
    in_deg_mask_kernel<<<gN, blk, 0, stream>>>(row_ptr, col, nm1, si_m1, n);
    scale_mask_kernel<<<gN, blk, 0, stream>>>(gate1, nm1, so_m1, si_m1, sarr, tarr, n);
    if (fast) {
        agg_f32_256_kernel<true, true><<<gAgg256, blk, 0, stream>>>(row_ptr, col, B, sarr, tarr,
                                                                    nullptr, Dh, Dl, n);
        gemm_rows_mfma_kernel<true><<<gemm_gK1, blk, 0, stream>>>(Dh, Dl, wsph + WO_ENC1,
                                                                  wspl + WO_ENC1, b_enc1, idx1, K1, C, 256, 256);
    } else {
        agg_f32_256_kernel<true, false><<<gAgg256, blk, 0, stream>>>(row_ptr, col, B, sarr, tarr,
                                                                     D, nullptr, nullptr, n);
        gemm_kernel<true><<<gemm_gv, blk, 0, stream>>>(D, W_enc1, b_enc1, nm1, nullptr, C, n, 256, 256);
    }

    // ---- pool1 ----
    score_kernel<<<gScore, blk, 0, stream>>>(C, W_p1, b_p1, nm1, scores2, keys2, n);
    run_topk(keys2, scores2, nm2, gate2, K2);
    if (fast) {
        hipMemsetAsync(ccnt + 1, 0, 4, stream);
        compact_kernel<<<gN, blk, 0, stream>>>(nm2, idx2, ccnt + 1, n);
    }

    // ---- bottleneck (mask m2, gated input) -> A ----
    hipMemsetAsync(so_m2, 0, (size_t)n * 4, stream);
    out_deg_mask_kernel<<<gE, blk, 0, stream>>>(src, dst, nm2, so_m2, E);
    in_deg_mask_kernel<<<gN, blk, 0, stream>>>(row_ptr, col, nm2, si_m2, n);
    scale_mask_kernel<<<gN, blk, 0, stream>>>(gate2, nm2, so_m2, si_m2, sarr, tarr, n);
    if (fast) {
        agg_f32_256_kernel<true, true><<<gAgg256, blk, 0, stream>>>(row_ptr, col, C, sarr, tarr,
                                                                    nullptr, Dh, Dl, n);
        gemm_rows_mfma_kernel<true><<<gemm_gK2, blk, 0, stream>>>(Dh, Dl, wsph + WO_BOT,
                                                                  wspl + WO_BOT, b_bot, idx2, K2, A, 256, 256);
    } else {
        agg_f32_256_kernel<true, false><<<gAgg256, blk, 0, stream>>>(row_ptr, col, C, sarr, tarr,
                                                                     D, nullptr, nullptr, n);
        gemm_kernel<true><<<gemm_gv, blk, 0, stream>>>(D, W_bot, b_bot, nm2, nullptr, A, n, 256, 256);
    }

    // ---- dec0: h = (m2? bot : 0) + hidden1, GCN mask m1 -> A ----
    add_mask_kernel<<<gAdd, blk, 0, stream>>>(A, C, fast ? nm2 : nullptr, n * 64);
    scale_mask_kernel<<<gN, blk, 0, stream>>>(nm1, nm1, so_m1, si_m1, sarr, tarr, n);
    if (fast) {
        agg_f32_256_kernel<true, true><<<gAgg256, blk, 0, stream>>>(row_ptr, col, A, sarr, tarr,
                                                                    nullptr, Dh, Dl, n);
        gemm_rows_mfma_kernel<true><<<gemm_gK1, blk, 0, stream>>>(Dh, Dl, wsph + WO_DEC0,
                                                                  wspl + WO_DEC0, b_dec0, idx1, K1, A, 256, 256);
    } else {
        agg_f32_256_kernel<true, false><<<gAgg256, blk, 0, stream>>>(row_ptr, col, A, sarr, tarr,
                                                                     D, nullptr, nullptr, n);
        gemm_kernel<true><<<gemm_gv, blk, 0, stream>>>(D, W_dec0, b_dec0, nm1, nullptr, A, n, 256, 256);
    }

    // ---- dec1 (reordered, final layer): h = (m1? dec0 : 0) + hidden0;
    //      P = (s0 .* h) @ W_dec1 -> C;  out_v = t0[v]*sum_N(v) P + b_dec1
    if (fast) {
        // fused: mask+add+rowscale+split done in GEMM A-staging (no add_split pass)
        gemm_dec1_kernel<<<gemm_g128, blk, 0, stream>>>(A, B, nm1, sF, wsph + WO_DEC1,
                                                        wspl + WO_DEC1, C, n, 256);
    } else {
        add_mask_kernel<<<gAdd, blk, 0, stream>>>(A, B, nullptr, n * 64);
        scale_full_kernel<<<gN, blk, 0, stream>>>(deg_out_i, deg_in_i, sarr, tarr, n);
        gemm_kernel<false><<<gemm_gv128, blk, 0, stream>>>(A, W_dec1, nullptr, nullptr, sF, C, n, 256, 128);
    }
    agg_bias_128_kernel<<<gAgg128, blk, 0, stream>>>(row_ptr, col, C, tF, b_dec1, out_f, n);

    (void)n_in; (void)out_size;
}